// Round 2
// baseline (1126.062 us; speedup 1.0000x reference)
//
#include <hip/hip_runtime.h>
#include <hip/hip_bf16.h>

// Problem constants (fixed by setup_inputs)
#define BB 4
#define TT 2048
#define VV 512
#define CC 512
#define HH 4
#define DD 128
#define NB2 128          // 2*NB
#define NROWS (BB*TT)    // 8192

__device__ __forceinline__ float dot4(float4 a, float4 b) {
    return a.x*b.x + a.y*b.y + a.z*b.z + a.w*b.w;
}
__device__ __forceinline__ void fma4(float4& acc, float s, float4 v) {
    acc.x = fmaf(s, v.x, acc.x); acc.y = fmaf(s, v.y, acc.y);
    acc.z = fmaf(s, v.z, acc.z); acc.w = fmaf(s, v.w, acc.w);
}

// ---------------------------------------------------------------------------
// Kernel 1: v_w[V][C] = basis @ v_coeffs.T ; o_wT[C][V] = (basis @ o_coeffs.T)^T * out_scale
// ---------------------------------------------------------------------------
__global__ __launch_bounds__(256) void prep_weights(
    const float* __restrict__ basis, const float* __restrict__ v_coeffs,
    const float* __restrict__ o_coeffs, const float* __restrict__ out_scale,
    float* __restrict__ v_w, float* __restrict__ o_wT)
{
    int idx = blockIdx.x * 256 + threadIdx.x;
    const int total = VV * CC;
    if (idx < total) {
        int vi = idx / CC, c = idx - vi * CC;
        const float4* bp = (const float4*)(basis + (size_t)vi * NB2);
        const float4* cp = (const float4*)(v_coeffs + (size_t)c * NB2);
        float s = 0.f;
        #pragma unroll
        for (int n = 0; n < NB2 / 4; ++n) s += dot4(bp[n], cp[n]);
        v_w[idx] = s;
    } else {
        int idx2 = idx - total;
        int c = idx2 / VV, vi = idx2 - c * VV;
        const float4* bp = (const float4*)(basis + (size_t)vi * NB2);
        const float4* cp = (const float4*)(o_coeffs + (size_t)c * NB2);
        float s = 0.f;
        #pragma unroll
        for (int n = 0; n < NB2 / 4; ++n) s += dot4(bp[n], cp[n]);
        o_wT[idx2] = s * out_scale[0];
    }
}

// ---------------------------------------------------------------------------
// Kernel 2: fp32 GEMM (NN): C[M,N] = A[M,K] @ B[K,N]. 64x64 tile, 4x4/thread.
// ---------------------------------------------------------------------------
__global__ __launch_bounds__(256) void gemm_nn(
    const float* __restrict__ A, const float* __restrict__ Bm,
    float* __restrict__ Cm, int M, int N, int K)
{
    __shared__ float As[16][72];   // A-tile transposed: As[k][m], padded
    __shared__ float Bs[16][72];   // B-tile: Bs[k][n], padded
    const int t  = threadIdx.x;
    const int n0 = blockIdx.x * 64;
    const int m0 = blockIdx.y * 64;
    const int tx = t & 15, ty = t >> 4;

    const int am = t >> 2, ak = (t & 3) * 4;   // A load: row am, 4 k's
    const int bk = t >> 4, bn = (t & 15) * 4;  // B load: row bk, 4 n's

    float acc[4][4] = {};

    for (int k0 = 0; k0 < K; k0 += 16) {
        float4 a = *(const float4*)(A + (size_t)(m0 + am) * K + k0 + ak);
        float4 b = *(const float4*)(Bm + (size_t)(k0 + bk) * N + n0 + bn);
        As[ak + 0][am] = a.x; As[ak + 1][am] = a.y;
        As[ak + 2][am] = a.z; As[ak + 3][am] = a.w;
        *(float4*)&Bs[bk][bn] = b;
        __syncthreads();
        #pragma unroll
        for (int kk = 0; kk < 16; ++kk) {
            float4 av = *(const float4*)&As[kk][ty * 4];
            float4 bv = *(const float4*)&Bs[kk][tx * 4];
            acc[0][0] = fmaf(av.x, bv.x, acc[0][0]);
            acc[0][1] = fmaf(av.x, bv.y, acc[0][1]);
            acc[0][2] = fmaf(av.x, bv.z, acc[0][2]);
            acc[0][3] = fmaf(av.x, bv.w, acc[0][3]);
            acc[1][0] = fmaf(av.y, bv.x, acc[1][0]);
            acc[1][1] = fmaf(av.y, bv.y, acc[1][1]);
            acc[1][2] = fmaf(av.y, bv.z, acc[1][2]);
            acc[1][3] = fmaf(av.y, bv.w, acc[1][3]);
            acc[2][0] = fmaf(av.z, bv.x, acc[2][0]);
            acc[2][1] = fmaf(av.z, bv.y, acc[2][1]);
            acc[2][2] = fmaf(av.z, bv.z, acc[2][2]);
            acc[2][3] = fmaf(av.z, bv.w, acc[2][3]);
            acc[3][0] = fmaf(av.w, bv.x, acc[3][0]);
            acc[3][1] = fmaf(av.w, bv.y, acc[3][1]);
            acc[3][2] = fmaf(av.w, bv.z, acc[3][2]);
            acc[3][3] = fmaf(av.w, bv.w, acc[3][3]);
        }
        __syncthreads();
    }
    #pragma unroll
    for (int r = 0; r < 4; ++r) {
        float* cp = Cm + (size_t)(m0 + ty * 4 + r) * N + n0 + tx * 4;
        *(float4*)cp = make_float4(acc[r][0], acc[r][1], acc[r][2], acc[r][3]);
    }
}

// ---------------------------------------------------------------------------
// Kernel 3: row-wise l2 normalize (over C=512), in place. 1 wave per row.
// ---------------------------------------------------------------------------
__global__ __launch_bounds__(256) void l2norm_rows(float* __restrict__ q, float* __restrict__ k)
{
    const int row  = blockIdx.x * 4 + (threadIdx.x >> 6);
    const int lane = threadIdx.x & 63;
    float* p = (blockIdx.y ? k : q) + (size_t)row * CC;
    float4* p4 = (float4*)p;
    float4 x0 = p4[lane];
    float4 x1 = p4[lane + 64];
    float ss = dot4(x0, x0) + dot4(x1, x1);
    #pragma unroll
    for (int off = 32; off > 0; off >>= 1) ss += __shfl_xor(ss, off, 64);
    float sc = 1.f / fmaxf(sqrtf(ss), 1e-12f);
    x0.x *= sc; x0.y *= sc; x0.z *= sc; x0.w *= sc;
    x1.x *= sc; x1.y *= sc; x1.z *= sc; x1.w *= sc;
    p4[lane] = x0; p4[lane + 64] = x1;
}

// ---------------------------------------------------------------------------
// Kernel 4: decayed reverse-causal attention.
// retrieved[i] = sum_{j>i} lam^(j-i-1) * (q_i . k_j) * v_j,  per (b,h)
// 32x32 tiles over (i,j), D=128 kept whole. ret may alias q (block reads
// its q tile into LDS before writing the identical ret region).
// ---------------------------------------------------------------------------
#define TI 32
#define TJ 32
#define LST 132

__global__ __launch_bounds__(256) void attention(
    const float* __restrict__ q, const float* __restrict__ k,
    const float* __restrict__ v, const float* __restrict__ dlog,
    float* __restrict__ ret)
{
    __shared__ float qs[TI][LST];
    __shared__ float ks[TJ][LST];
    __shared__ float vs[TJ][LST];
    __shared__ float ss[TI][TJ + 1];

    const int it = blockIdx.x;           // 0..63
    const int bh = blockIdx.y;           // 0..15
    const int b = bh >> 2, h = bh & 3;
    const float lam = 1.f / (1.f + expf(-dlog[h]));
    const float l2lam = log2f(lam);
    const int i0 = it * TI;
    const int t = threadIdx.x;

    const size_t base = (size_t)(b * TT) * CC + h * DD;
    const float* qbase = q + base;
    const float* kbase = k + base;
    const float* vbase = v + base;

    const int lr = t >> 3;           // tile row 0..31 for loads
    const int ld = (t & 7) * 16;     // 16 floats per thread per row
    {
        const float* src = qbase + (size_t)(i0 + lr) * CC + ld;
        #pragma unroll
        for (int i = 0; i < 4; ++i)
            *(float4*)&qs[lr][ld + 4 * i] = *(const float4*)(src + 4 * i);
    }

    const int si = t & 15;           // score rows si*2, si*2+1 (also accum rows)
    const int sj = t >> 4;           // score cols sj*2, sj*2+1 ; accum cols sj*8..
    float4 acc00 = {0,0,0,0}, acc01 = {0,0,0,0};
    float4 acc10 = {0,0,0,0}, acc11 = {0,0,0,0};

    for (int jt = it; jt < TT / TJ; ++jt) {
        const int j0 = jt * TJ;
        __syncthreads();  // prev accumulate done before ks/vs overwrite
        {
            const float* ksrc = kbase + (size_t)(j0 + lr) * CC + ld;
            const float* vsrc = vbase + (size_t)(j0 + lr) * CC + ld;
            #pragma unroll
            for (int i = 0; i < 4; ++i) {
                *(float4*)&ks[lr][ld + 4 * i] = *(const float4*)(ksrc + 4 * i);
                *(float4*)&vs[lr][ld + 4 * i] = *(const float4*)(vsrc + 4 * i);
            }
        }
        __syncthreads();
        // scores: 2x2 per thread over full D
        float s00 = 0.f, s01 = 0.f, s10 = 0.f, s11 = 0.f;
        #pragma unroll 8
        for (int d4 = 0; d4 < DD / 4; ++d4) {
            float4 q0 = *(const float4*)&qs[si * 2 + 0][d4 * 4];
            float4 q1 = *(const float4*)&qs[si * 2 + 1][d4 * 4];
            float4 k0 = *(const float4*)&ks[sj * 2 + 0][d4 * 4];
            float4 k1 = *(const float4*)&ks[sj * 2 + 1][d4 * 4];
            s00 += dot4(q0, k0); s01 += dot4(q0, k1);
            s10 += dot4(q1, k0); s11 += dot4(q1, k1);
        }
        // rows: r0 = i0+si*2, r1 = r0+1 ; cols: c0 = j0+sj*2, c1 = c0+1
        // weight(i,j) = (j>i) ? lam^(j-i-1) : 0
        const int di = (j0 + sj * 2) - (i0 + si * 2);   // c0 - r0
        const float w_m1 = exp2f((float)(di - 1) * l2lam);  // e = di-1
        const float w_0  = exp2f((float)(di)     * l2lam);  // e = di
        const float w_m2 = exp2f((float)(di - 2) * l2lam);  // e = di-2
        ss[si*2+0][sj*2+0] = (di > 0) ? s00 * w_m1 : 0.f;   // (r0,c0): e=di-1, j>i iff di>0
        ss[si*2+0][sj*2+1] = (di >= 0) ? s01 * w_0 : 0.f;   // (r0,c1): e=di,   j>i iff di+1>0
        ss[si*2+1][sj*2+0] = (di > 1) ? s10 * w_m2 : 0.f;   // (r1,c0): e=di-2, j>i iff di>1
        ss[si*2+1][sj*2+1] = (di > 0) ? s11 * w_m1 : 0.f;   // (r1,c1): e=di-1, j>i iff di>0
        __syncthreads();
        // accumulate: rows si*2,si*2+1 ; cols sj*8..sj*8+7
        #pragma unroll 8
        for (int j = 0; j < TJ; ++j) {
            float w0 = ss[si * 2 + 0][j];
            float w1 = ss[si * 2 + 1][j];
            float4 v0 = *(const float4*)&vs[j][sj * 8 + 0];
            float4 v1 = *(const float4*)&vs[j][sj * 8 + 4];
            fma4(acc00, w0, v0); fma4(acc01, w0, v1);
            fma4(acc10, w1, v0); fma4(acc11, w1, v1);
        }
    }

    float* rbase = ret + base;
    *(float4*)(rbase + (size_t)(i0 + si * 2 + 0) * CC + sj * 8 + 0) = acc00;
    *(float4*)(rbase + (size_t)(i0 + si * 2 + 0) * CC + sj * 8 + 4) = acc01;
    *(float4*)(rbase + (size_t)(i0 + si * 2 + 1) * CC + sj * 8 + 0) = acc10;
    *(float4*)(rbase + (size_t)(i0 + si * 2 + 1) * CC + sj * 8 + 4) = acc11;
}

// ---------------------------------------------------------------------------
extern "C" void kernel_launch(void* const* d_in, const int* in_sizes, int n_in,
                              void* d_out, int out_size, void* d_ws, size_t ws_size,
                              hipStream_t stream) {
    const float* x         = (const float*)d_in[0];
    const float* basis     = (const float*)d_in[1];
    const float* qw        = (const float*)d_in[2];
    const float* kw        = (const float*)d_in[3];
    const float* v_coeffs  = (const float*)d_in[4];
    const float* o_coeffs  = (const float*)d_in[5];
    const float* dlog      = (const float*)d_in[6];
    const float* out_scale = (const float*)d_in[7];
    float* out             = (float*)d_out;   // reference output dtype is fp32

    float* ws   = (float*)d_ws;
    float* qbuf = ws;                              // 8192*512
    float* kbuf = ws + (size_t)NROWS * CC;         // 8192*512
    float* vbuf = ws + 2 * (size_t)NROWS * CC;     // 8192*512
    float* v_w  = ws + 3 * (size_t)NROWS * CC;     // 512*512
    float* o_wT = v_w + (size_t)VV * CC;           // 512*512
    float* ret  = qbuf;                            // alias (safe: see attention)

    // 1. small weight GEMMs
    prep_weights<<<2 * VV * CC / 256, 256, 0, stream>>>(basis, v_coeffs, o_coeffs,
                                                        out_scale, v_w, o_wT);
    // 2. projections
    dim3 ggrid(CC / 64, NROWS / 64);
    gemm_nn<<<ggrid, 256, 0, stream>>>(x, qw, qbuf, NROWS, CC, VV);
    gemm_nn<<<ggrid, 256, 0, stream>>>(x, kw, kbuf, NROWS, CC, VV);
    gemm_nn<<<ggrid, 256, 0, stream>>>(x, v_w, vbuf, NROWS, CC, VV);
    // 3. l2norm q,k
    l2norm_rows<<<dim3(NROWS / 4, 2), 256, 0, stream>>>(qbuf, kbuf);
    // 4. attention
    attention<<<dim3(TT / TI, BB * HH), 256, 0, stream>>>(qbuf, kbuf, vbuf, dlog, ret);
    // 5. output projection (o_wT already includes out_scale), fp32 store
    gemm_nn<<<ggrid, 256, 0, stream>>>(ret, o_wT, out, NROWS, VV, CC);
}

// Round 3
// 529.379 us; speedup vs baseline: 2.1271x; 2.1271x over previous
//
#include <hip/hip_runtime.h>
#include <hip/hip_bf16.h>

// Problem constants (fixed by setup_inputs)
#define BB 4
#define TT 2048
#define VV 512
#define CC 512
#define HH 4
#define DD 128
#define NB2 128          // 2*NB
#define NROWS (BB*TT)    // 8192
#define QC 64            // linear-attention chunk length
#define NCH (TT/QC)      // 32 chunks per sequence

__device__ __forceinline__ float dot4(float4 a, float4 b) {
    return a.x*b.x + a.y*b.y + a.z*b.z + a.w*b.w;
}
__device__ __forceinline__ void fma4(float4& acc, float s, float4 v) {
    acc.x = fmaf(s, v.x, acc.x); acc.y = fmaf(s, v.y, acc.y);
    acc.z = fmaf(s, v.z, acc.z); acc.w = fmaf(s, v.w, acc.w);
}

// ---------------------------------------------------------------------------
// Kernel 1: v_w[V][C] = basis @ v_coeffs.T ; o_wT[C][V] = (basis @ o_coeffs.T)^T * out_scale
// ---------------------------------------------------------------------------
__global__ __launch_bounds__(256) void prep_weights(
    const float* __restrict__ basis, const float* __restrict__ v_coeffs,
    const float* __restrict__ o_coeffs, const float* __restrict__ out_scale,
    float* __restrict__ v_w, float* __restrict__ o_wT)
{
    int idx = blockIdx.x * 256 + threadIdx.x;
    const int total = VV * CC;
    if (idx < total) {
        int vi = idx / CC, c = idx - vi * CC;
        const float4* bp = (const float4*)(basis + (size_t)vi * NB2);
        const float4* cp = (const float4*)(v_coeffs + (size_t)c * NB2);
        float s = 0.f;
        #pragma unroll
        for (int n = 0; n < NB2 / 4; ++n) s += dot4(bp[n], cp[n]);
        v_w[idx] = s;
    } else {
        int idx2 = idx - total;
        int c = idx2 / VV, vi = idx2 - c * VV;
        const float4* bp = (const float4*)(basis + (size_t)vi * NB2);
        const float4* cp = (const float4*)(o_coeffs + (size_t)c * NB2);
        float s = 0.f;
        #pragma unroll
        for (int n = 0; n < NB2 / 4; ++n) s += dot4(bp[n], cp[n]);
        o_wT[idx2] = s * out_scale[0];
    }
}

// ---------------------------------------------------------------------------
// Kernel 2: fp32 GEMM (NN): C[M,N] = A[M,K] @ B[K,N]. 64x64 tile, 4x4/thread.
// ---------------------------------------------------------------------------
__global__ __launch_bounds__(256) void gemm_nn(
    const float* __restrict__ A, const float* __restrict__ Bm,
    float* __restrict__ Cm, int M, int N, int K)
{
    __shared__ float As[16][72];   // A-tile transposed: As[k][m], padded
    __shared__ float Bs[16][72];   // B-tile: Bs[k][n], padded
    const int t  = threadIdx.x;
    const int n0 = blockIdx.x * 64;
    const int m0 = blockIdx.y * 64;
    const int tx = t & 15, ty = t >> 4;

    const int am = t >> 2, ak = (t & 3) * 4;   // A load: row am, 4 k's
    const int bk = t >> 4, bn = (t & 15) * 4;  // B load: row bk, 4 n's

    float acc[4][4] = {};

    for (int k0 = 0; k0 < K; k0 += 16) {
        float4 a = *(const float4*)(A + (size_t)(m0 + am) * K + k0 + ak);
        float4 b = *(const float4*)(Bm + (size_t)(k0 + bk) * N + n0 + bn);
        As[ak + 0][am] = a.x; As[ak + 1][am] = a.y;
        As[ak + 2][am] = a.z; As[ak + 3][am] = a.w;
        *(float4*)&Bs[bk][bn] = b;
        __syncthreads();
        #pragma unroll
        for (int kk = 0; kk < 16; ++kk) {
            float4 av = *(const float4*)&As[kk][ty * 4];
            float4 bv = *(const float4*)&Bs[kk][tx * 4];
            acc[0][0] = fmaf(av.x, bv.x, acc[0][0]);
            acc[0][1] = fmaf(av.x, bv.y, acc[0][1]);
            acc[0][2] = fmaf(av.x, bv.z, acc[0][2]);
            acc[0][3] = fmaf(av.x, bv.w, acc[0][3]);
            acc[1][0] = fmaf(av.y, bv.x, acc[1][0]);
            acc[1][1] = fmaf(av.y, bv.y, acc[1][1]);
            acc[1][2] = fmaf(av.y, bv.z, acc[1][2]);
            acc[1][3] = fmaf(av.y, bv.w, acc[1][3]);
            acc[2][0] = fmaf(av.z, bv.x, acc[2][0]);
            acc[2][1] = fmaf(av.z, bv.y, acc[2][1]);
            acc[2][2] = fmaf(av.z, bv.z, acc[2][2]);
            acc[2][3] = fmaf(av.z, bv.w, acc[2][3]);
            acc[3][0] = fmaf(av.w, bv.x, acc[3][0]);
            acc[3][1] = fmaf(av.w, bv.y, acc[3][1]);
            acc[3][2] = fmaf(av.w, bv.z, acc[3][2]);
            acc[3][3] = fmaf(av.w, bv.w, acc[3][3]);
        }
        __syncthreads();
    }
    #pragma unroll
    for (int r = 0; r < 4; ++r) {
        float* cp = Cm + (size_t)(m0 + ty * 4 + r) * N + n0 + tx * 4;
        *(float4*)cp = make_float4(acc[r][0], acc[r][1], acc[r][2], acc[r][3]);
    }
}

// ---------------------------------------------------------------------------
// Kernel 3: row-wise l2 normalize (over C=512), in place. 1 wave per row.
// ---------------------------------------------------------------------------
__global__ __launch_bounds__(256) void l2norm_rows(float* __restrict__ q, float* __restrict__ k)
{
    const int row  = blockIdx.x * 4 + (threadIdx.x >> 6);
    const int lane = threadIdx.x & 63;
    float* p = (blockIdx.y ? k : q) + (size_t)row * CC;
    float4* p4 = (float4*)p;
    float4 x0 = p4[lane];
    float4 x1 = p4[lane + 64];
    float ss = dot4(x0, x0) + dot4(x1, x1);
    #pragma unroll
    for (int off = 32; off > 0; off >>= 1) ss += __shfl_xor(ss, off, 64);
    float sc = 1.f / fmaxf(sqrtf(ss), 1e-12f);
    x0.x *= sc; x0.y *= sc; x0.z *= sc; x0.w *= sc;
    x1.x *= sc; x1.y *= sc; x1.z *= sc; x1.w *= sc;
    p4[lane] = x0; p4[lane + 64] = x1;
}

// ---------------------------------------------------------------------------
// Kernel 4a: per-chunk local states.
// S_local[bh][c][e][d] = sum_{j=0..63} lam^j * k[c0+j][e] * v[c0+j][d]
// One block per (c, bh); 8x8 outer-product register tile per thread.
// ---------------------------------------------------------------------------
__global__ __launch_bounds__(256) void state_local(
    const float* __restrict__ k, const float* __restrict__ v,
    const float* __restrict__ dlog, float* __restrict__ states)
{
    __shared__ float ksA[16][132];
    __shared__ float vsA[16][132];
    const int c  = blockIdx.x;
    const int bh = blockIdx.y;
    const int b = bh >> 2, h = bh & 3;
    const float lam = 1.f / (1.f + __expf(-dlog[h]));
    const float l2lam = log2f(lam);
    const int t = threadIdx.x;
    const int tx = t & 15, ty = t >> 4;
    const size_t gbase = ((size_t)(b * TT + c * QC)) * CC + h * DD;

    float acc[8][8] = {};

    for (int j0 = 0; j0 < QC; j0 += 16) {
        __syncthreads();
        #pragma unroll
        for (int s = 0; s < 2; ++s) {
            int f4 = s * 256 + t;
            int r = f4 >> 5, c4 = (f4 & 31) * 4;
            float4 kv = *(const float4*)(k + gbase + (size_t)(j0 + r) * CC + c4);
            float4 vv = *(const float4*)(v + gbase + (size_t)(j0 + r) * CC + c4);
            float w = exp2f((float)(j0 + r) * l2lam);
            kv.x *= w; kv.y *= w; kv.z *= w; kv.w *= w;
            *(float4*)&ksA[r][c4] = kv;
            *(float4*)&vsA[r][c4] = vv;
        }
        __syncthreads();
        #pragma unroll
        for (int jj = 0; jj < 16; ++jj) {
            float4 ka0 = *(const float4*)&ksA[jj][ty * 8];
            float4 ka1 = *(const float4*)&ksA[jj][ty * 8 + 4];
            float4 va0 = *(const float4*)&vsA[jj][tx * 8];
            float4 va1 = *(const float4*)&vsA[jj][tx * 8 + 4];
            float ke[8] = {ka0.x, ka0.y, ka0.z, ka0.w, ka1.x, ka1.y, ka1.z, ka1.w};
            float vd[8] = {va0.x, va0.y, va0.z, va0.w, va1.x, va1.y, va1.z, va1.w};
            #pragma unroll
            for (int a = 0; a < 8; ++a)
                #pragma unroll
                for (int d = 0; d < 8; ++d)
                    acc[a][d] = fmaf(ke[a], vd[d], acc[a][d]);
        }
    }
    float* so = states + ((size_t)(bh * NCH + c) << 14);
    #pragma unroll
    for (int a = 0; a < 8; ++a) {
        float* p = so + (ty * 8 + a) * DD + tx * 8;
        *(float4*)(p + 0) = make_float4(acc[a][0], acc[a][1], acc[a][2], acc[a][3]);
        *(float4*)(p + 4) = make_float4(acc[a][4], acc[a][5], acc[a][6], acc[a][7]);
    }
}

// ---------------------------------------------------------------------------
// Kernel 4b: in-place suffix combine over chunks (per bh).
// After this, states[bh][c] = S_{(c+1)*QC} = cross-state for chunk c.
// ---------------------------------------------------------------------------
__global__ __launch_bounds__(256) void state_combine(
    const float* __restrict__ dlog, float* __restrict__ states)
{
    const int bh = blockIdx.x;
    const int h = bh & 3;
    const float lam = 1.f / (1.f + __expf(-dlog[h]));
    const float lamQ = exp2f((float)QC * log2f(lam));
    const int t = threadIdx.x;
    float4 run[16];
    #pragma unroll
    for (int s = 0; s < 16; ++s) run[s] = make_float4(0.f, 0.f, 0.f, 0.f);
    float* base = states + ((size_t)(bh * NCH) << 14);
    for (int c = NCH - 1; c >= 0; --c) {
        float4* p = (float4*)(base + ((size_t)c << 14)) + t;
        #pragma unroll
        for (int s = 0; s < 16; ++s) {
            float4 tmp = p[s * 256];
            p[s * 256] = run[s];
            run[s].x = fmaf(lamQ, run[s].x, tmp.x);
            run[s].y = fmaf(lamQ, run[s].y, tmp.y);
            run[s].z = fmaf(lamQ, run[s].z, tmp.z);
            run[s].w = fmaf(lamQ, run[s].w, tmp.w);
        }
    }
}

// ---------------------------------------------------------------------------
// Kernel 4c: cross term. ret[c0+ii][:] = lam^(63-ii) * q[c0+ii] @ S  (S=[128][128])
// One block per (c, bh); A staged transposed+scaled in LDS; B tiled 32 rows.
// ---------------------------------------------------------------------------
__global__ __launch_bounds__(256) void cross_term(
    const float* __restrict__ q, const float* __restrict__ states,
    const float* __restrict__ dlog, float* __restrict__ ret)
{
    __shared__ float as[DD][68];     // as[e][ii] = lam^(63-ii) q[ii][e]
    __shared__ float bs[32][132];    // S row-tile
    const int c = blockIdx.x, bh = blockIdx.y;
    const int b = bh >> 2, h = bh & 3;
    const float lam = 1.f / (1.f + __expf(-dlog[h]));
    const float l2lam = log2f(lam);
    const int t = threadIdx.x;
    const size_t gq = ((size_t)(b * TT + c * QC)) * CC + h * DD;

    #pragma unroll
    for (int s = 0; s < 8; ++s) {
        int f4 = s * 256 + t;
        int ii = f4 >> 5, c4 = (f4 & 31) * 4;
        float4 qv = *(const float4*)(q + gq + (size_t)ii * CC + c4);
        float w = exp2f((float)(QC - 1 - ii) * l2lam);
        as[c4 + 0][ii] = qv.x * w;
        as[c4 + 1][ii] = qv.y * w;
        as[c4 + 2][ii] = qv.z * w;
        as[c4 + 3][ii] = qv.w * w;
    }

    const float* sp = states + ((size_t)(bh * NCH + c) << 14);
    const int ro = (t & 15) * 4, dc = (t >> 4) * 8;
    float4 accL[4] = {}, accR[4] = {};

    for (int et = 0; et < 4; ++et) {
        __syncthreads();   // as ready (first) / bs consumed (later)
        #pragma unroll
        for (int s = 0; s < 4; ++s) {
            int f4 = s * 256 + t;
            int r = f4 >> 5, c4 = (f4 & 31) * 4;
            *(float4*)&bs[r][c4] = *(const float4*)(sp + ((et * 32 + r) << 7) + c4);
        }
        __syncthreads();
        #pragma unroll
        for (int e = 0; e < 32; ++e) {
            float4 af = *(const float4*)&as[et * 32 + e][ro];
            float4 b0 = *(const float4*)&bs[e][dc];
            float4 b1 = *(const float4*)&bs[e][dc + 4];
            fma4(accL[0], af.x, b0); fma4(accR[0], af.x, b1);
            fma4(accL[1], af.y, b0); fma4(accR[1], af.y, b1);
            fma4(accL[2], af.z, b0); fma4(accR[2], af.z, b1);
            fma4(accL[3], af.w, b0); fma4(accR[3], af.w, b1);
        }
    }
    #pragma unroll
    for (int r = 0; r < 4; ++r) {
        float* rp = ret + ((size_t)(b * TT + c * QC + ro + r)) * CC + h * DD + dc;
        *(float4*)(rp + 0) = accL[r];
        *(float4*)(rp + 4) = accR[r];
    }
}

// ---------------------------------------------------------------------------
// Kernel 4d: intra-chunk attention (verified decay/mask logic), accumulates
// into ret (+=). Block it covers i-rows [it*32, it*32+32); j-tiles restricted
// to its own QC=64 chunk (1 or 2 tiles).
// ---------------------------------------------------------------------------
#define TI 32
#define TJ 32
#define LST 132

__global__ __launch_bounds__(256) void attention_intra(
    const float* __restrict__ q, const float* __restrict__ k,
    const float* __restrict__ v, const float* __restrict__ dlog,
    float* __restrict__ ret)
{
    __shared__ float qs[TI][LST];
    __shared__ float ks[TJ][LST];
    __shared__ float vs[TJ][LST];
    __shared__ float ss[TI][TJ + 1];

    const int it = blockIdx.x;           // 0..63
    const int bh = blockIdx.y;           // 0..15
    const int b = bh >> 2, h = bh & 3;
    const float lam = 1.f / (1.f + __expf(-dlog[h]));
    const float l2lam = log2f(lam);
    const int i0 = it * TI;
    const int t = threadIdx.x;

    const size_t base = (size_t)(b * TT) * CC + h * DD;
    const float* qbase = q + base;
    const float* kbase = k + base;
    const float* vbase = v + base;

    const int lr = t >> 3;
    const int ld = (t & 7) * 16;
    {
        const float* src = qbase + (size_t)(i0 + lr) * CC + ld;
        #pragma unroll
        for (int i = 0; i < 4; ++i)
            *(float4*)&qs[lr][ld + 4 * i] = *(const float4*)(src + 4 * i);
    }

    const int si = t & 15;
    const int sj = t >> 4;
    float4 acc00 = {0,0,0,0}, acc01 = {0,0,0,0};
    float4 acc10 = {0,0,0,0}, acc11 = {0,0,0,0};

    const int jt_end = 2 * (it >> 1) + 2;   // exclusive: j-tiles within chunk
    for (int jt = it; jt < jt_end; ++jt) {
        const int j0 = jt * TJ;
        __syncthreads();
        {
            const float* ksrc = kbase + (size_t)(j0 + lr) * CC + ld;
            const float* vsrc = vbase + (size_t)(j0 + lr) * CC + ld;
            #pragma unroll
            for (int i = 0; i < 4; ++i) {
                *(float4*)&ks[lr][ld + 4 * i] = *(const float4*)(ksrc + 4 * i);
                *(float4*)&vs[lr][ld + 4 * i] = *(const float4*)(vsrc + 4 * i);
            }
        }
        __syncthreads();
        float s00 = 0.f, s01 = 0.f, s10 = 0.f, s11 = 0.f;
        #pragma unroll 8
        for (int d4 = 0; d4 < DD / 4; ++d4) {
            float4 q0 = *(const float4*)&qs[si * 2 + 0][d4 * 4];
            float4 q1 = *(const float4*)&qs[si * 2 + 1][d4 * 4];
            float4 k0 = *(const float4*)&ks[sj * 2 + 0][d4 * 4];
            float4 k1 = *(const float4*)&ks[sj * 2 + 1][d4 * 4];
            s00 += dot4(q0, k0); s01 += dot4(q0, k1);
            s10 += dot4(q1, k0); s11 += dot4(q1, k1);
        }
        // weight(i,j) = (j>i) ? lam^(j-i-1) : 0
        const int di = (j0 + sj * 2) - (i0 + si * 2);
        const float w_m1 = exp2f((float)(di - 1) * l2lam);
        const float w_0  = exp2f((float)(di)     * l2lam);
        const float w_m2 = exp2f((float)(di - 2) * l2lam);
        ss[si*2+0][sj*2+0] = (di > 0)  ? s00 * w_m1 : 0.f;
        ss[si*2+0][sj*2+1] = (di >= 0) ? s01 * w_0  : 0.f;
        ss[si*2+1][sj*2+0] = (di > 1)  ? s10 * w_m2 : 0.f;
        ss[si*2+1][sj*2+1] = (di > 0)  ? s11 * w_m1 : 0.f;
        __syncthreads();
        #pragma unroll 8
        for (int j = 0; j < TJ; ++j) {
            float w0 = ss[si * 2 + 0][j];
            float w1 = ss[si * 2 + 1][j];
            float4 v0 = *(const float4*)&vs[j][sj * 8 + 0];
            float4 v1 = *(const float4*)&vs[j][sj * 8 + 4];
            fma4(acc00, w0, v0); fma4(acc01, w0, v1);
            fma4(acc10, w1, v0); fma4(acc11, w1, v1);
        }
    }

    float* rbase = ret + base;
    float* r0 = rbase + (size_t)(i0 + si * 2 + 0) * CC + sj * 8;
    float* r1 = rbase + (size_t)(i0 + si * 2 + 1) * CC + sj * 8;
    float4 o;
    o = *(float4*)(r0 + 0); o.x += acc00.x; o.y += acc00.y; o.z += acc00.z; o.w += acc00.w; *(float4*)(r0 + 0) = o;
    o = *(float4*)(r0 + 4); o.x += acc01.x; o.y += acc01.y; o.z += acc01.z; o.w += acc01.w; *(float4*)(r0 + 4) = o;
    o = *(float4*)(r1 + 0); o.x += acc10.x; o.y += acc10.y; o.z += acc10.z; o.w += acc10.w; *(float4*)(r1 + 0) = o;
    o = *(float4*)(r1 + 4); o.x += acc11.x; o.y += acc11.y; o.z += acc11.z; o.w += acc11.w; *(float4*)(r1 + 4) = o;
}

// ---------------------------------------------------------------------------
extern "C" void kernel_launch(void* const* d_in, const int* in_sizes, int n_in,
                              void* d_out, int out_size, void* d_ws, size_t ws_size,
                              hipStream_t stream) {
    const float* x         = (const float*)d_in[0];
    const float* basis     = (const float*)d_in[1];
    const float* qw        = (const float*)d_in[2];
    const float* kw        = (const float*)d_in[3];
    const float* v_coeffs  = (const float*)d_in[4];
    const float* o_coeffs  = (const float*)d_in[5];
    const float* dlog      = (const float*)d_in[6];
    const float* out_scale = (const float*)d_in[7];
    float* out             = (float*)d_out;   // reference output dtype is fp32

    float* ws     = (float*)d_ws;
    float* qbuf   = ws;                               // 8192*512
    float* kbuf   = qbuf + (size_t)NROWS * CC;        // 8192*512
    float* vbuf   = kbuf + (size_t)NROWS * CC;        // 8192*512
    float* ret    = vbuf + (size_t)NROWS * CC;        // 8192*512
    float* v_w    = ret  + (size_t)NROWS * CC;        // 512*512
    float* o_wT   = v_w  + (size_t)VV * CC;           // 512*512
    float* states = o_wT + (size_t)VV * CC;           // 16*32*128*128 = 8.39M

    // 1. small weight GEMMs
    prep_weights<<<2 * VV * CC / 256, 256, 0, stream>>>(basis, v_coeffs, o_coeffs,
                                                        out_scale, v_w, o_wT);
    // 2. projections
    dim3 ggrid(CC / 64, NROWS / 64);
    gemm_nn<<<ggrid, 256, 0, stream>>>(x, qw, qbuf, NROWS, CC, VV);
    gemm_nn<<<ggrid, 256, 0, stream>>>(x, kw, kbuf, NROWS, CC, VV);
    gemm_nn<<<ggrid, 256, 0, stream>>>(x, v_w, vbuf, NROWS, CC, VV);
    // 3. l2norm q,k
    l2norm_rows<<<dim3(NROWS / 4, 2), 256, 0, stream>>>(qbuf, kbuf);
    // 4. chunked linear attention
    state_local  <<<dim3(NCH, BB * HH), 256, 0, stream>>>(kbuf, vbuf, dlog, states);
    state_combine<<<BB * HH, 256, 0, stream>>>(dlog, states);
    cross_term   <<<dim3(NCH, BB * HH), 256, 0, stream>>>(qbuf, states, dlog, ret);
    attention_intra<<<dim3(TT / TI, BB * HH), 256, 0, stream>>>(qbuf, kbuf, vbuf, dlog, ret);
    // 5. output projection (o_wT already includes out_scale)
    gemm_nn<<<ggrid, 256, 0, stream>>>(ret, o_wT, out, NROWS, VV, CC);
}

// Round 4
// 297.740 us; speedup vs baseline: 3.7820x; 1.7780x over previous
//
#include <hip/hip_runtime.h>
#include <hip/hip_bf16.h>

// Problem constants (fixed by setup_inputs)
#define BB 4
#define TT 2048
#define VV 512
#define CC 512
#define HH 4
#define DD 128
#define NB2 128          // 2*NB
#define NROWS (BB*TT)    // 8192
#define QC 64            // linear-attention chunk length
#define NCH (TT/QC)      // 32 chunks per sequence

typedef __attribute__((ext_vector_type(8))) short bf16x8;
typedef __attribute__((ext_vector_type(4))) float f32x4;

__device__ __forceinline__ float dot4(float4 a, float4 b) {
    return a.x*b.x + a.y*b.y + a.z*b.z + a.w*b.w;
}
__device__ __forceinline__ void fma4(float4& acc, float s, float4 v) {
    acc.x = fmaf(s, v.x, acc.x); acc.y = fmaf(s, v.y, acc.y);
    acc.z = fmaf(s, v.z, acc.z); acc.w = fmaf(s, v.w, acc.w);
}
__device__ __forceinline__ void gl_lds16(const void* g, void* l) {
    __builtin_amdgcn_global_load_lds(
        (const __attribute__((address_space(1))) unsigned int*)g,
        (__attribute__((address_space(3))) unsigned int*)l, 16, 0, 0);
}
__device__ __forceinline__ void store_bf16x8(__hip_bfloat16* p, float4 a, float4 b) {
    __hip_bfloat16 h[8] = {__float2bfloat16(a.x), __float2bfloat16(a.y),
                           __float2bfloat16(a.z), __float2bfloat16(a.w),
                           __float2bfloat16(b.x), __float2bfloat16(b.y),
                           __float2bfloat16(b.z), __float2bfloat16(b.w)};
    *(uint4*)p = *(uint4*)h;
}

// ---------------------------------------------------------------------------
// x (fp32) -> xb (bf16), element-wise, float4-vectorized
// ---------------------------------------------------------------------------
__global__ __launch_bounds__(256) void cvt_bf16(
    const float* __restrict__ in, __hip_bfloat16* __restrict__ out)
{
    int i = blockIdx.x * 256 + threadIdx.x;   // per float4
    float4 v = ((const float4*)in)[i];
    __hip_bfloat16 h[4] = {__float2bfloat16(v.x), __float2bfloat16(v.y),
                           __float2bfloat16(v.z), __float2bfloat16(v.w)};
    ((uint2*)out)[i] = *(uint2*)h;
}

// ---------------------------------------------------------------------------
// 512x512 transpose + convert: outT[c][v] = in[v][c] as bf16
// ---------------------------------------------------------------------------
__global__ __launch_bounds__(256) void transpose_cvt(
    const float* __restrict__ in, __hip_bfloat16* __restrict__ outT)
{
    __shared__ float tile[32][33];
    const int bx = blockIdx.x * 32, by = blockIdx.y * 32;
    const int tx = threadIdx.x & 31, ty = threadIdx.x >> 5;   // 32 x 8
    #pragma unroll
    for (int r = 0; r < 32; r += 8)
        tile[ty + r][tx] = in[(size_t)(by + ty + r) * CC + bx + tx];
    __syncthreads();
    #pragma unroll
    for (int r = 0; r < 32; r += 8)
        outT[(size_t)(bx + ty + r) * VV + by + tx] = __float2bfloat16(tile[tx][ty + r]);
}

// ---------------------------------------------------------------------------
// prep: v_wT[c][v] = (basis @ v_coeffs.T)^T  (bf16)
//       o_ws[v][c] = (basis @ o_coeffs.T) * out_scale (bf16)
// ---------------------------------------------------------------------------
__global__ __launch_bounds__(256) void prep_weights(
    const float* __restrict__ basis, const float* __restrict__ v_coeffs,
    const float* __restrict__ o_coeffs, const float* __restrict__ out_scale,
    __hip_bfloat16* __restrict__ v_wT, __hip_bfloat16* __restrict__ o_ws)
{
    int idx = blockIdx.x * 256 + threadIdx.x;
    const int total = VV * CC;
    if (idx < total) {
        int c = idx >> 9, vi = idx & 511;      // v_wT[c][vi]
        const float4* bp = (const float4*)(basis + (size_t)vi * NB2);
        const float4* cp = (const float4*)(v_coeffs + (size_t)c * NB2);
        float s = 0.f;
        #pragma unroll
        for (int n = 0; n < NB2 / 4; ++n) s += dot4(bp[n], cp[n]);
        v_wT[idx] = __float2bfloat16(s);
    } else {
        int idx2 = idx - total;
        int vi = idx2 >> 9, c = idx2 & 511;    // o_ws[vi][c]
        const float4* bp = (const float4*)(basis + (size_t)vi * NB2);
        const float4* cp = (const float4*)(o_coeffs + (size_t)c * NB2);
        float s = 0.f;
        #pragma unroll
        for (int n = 0; n < NB2 / 4; ++n) s += dot4(bp[n], cp[n]);
        o_ws[idx2] = __float2bfloat16(s * out_scale[0]);
    }
}

// ---------------------------------------------------------------------------
// bf16 MFMA GEMM: C[M,N] fp32 = A[M,K] @ Bt[N,K]^T, 128x128 tile, BK=32.
// m97 recipe: global_load_lds width 16, [c][row] slot layout, ds_read_b128.
// ---------------------------------------------------------------------------
__global__ __launch_bounds__(256) void gemm_bf16(
    const __hip_bfloat16* __restrict__ Ab, const __hip_bfloat16* __restrict__ Btb,
    float* __restrict__ C, int M, int N, int K)
{
    __shared__ __align__(16) unsigned short As[4096];  // 4 k-quarters x 128 rows x 8 bf16
    __shared__ __align__(16) unsigned short Bs[4096];
    const unsigned short* A  = (const unsigned short*)Ab;
    const unsigned short* Bt = (const unsigned short*)Btb;
    const int t = threadIdx.x;
    const int wave = t >> 6, lane = t & 63;
    const int q = lane >> 4, l16 = lane & 15;
    const int m0 = blockIdx.y * 128, n0 = blockIdx.x * 128;
    const int wm = (wave >> 1) * 64, wn = (wave & 1) * 64;

    // staging slots for this thread (slot = c*128 + row; lds = base + lane*16)
    const int sA0 = wave * 128 + lane, sA1 = sA0 + 64;
    const int r0_ = sA0 & 127, c0_ = sA0 >> 7;
    const int r1_ = sA1 & 127, c1_ = sA1 >> 7;
    const unsigned short* ga0 = A  + (size_t)(m0 + r0_) * K + c0_ * 8;
    const unsigned short* ga1 = A  + (size_t)(m0 + r1_) * K + c1_ * 8;
    const unsigned short* gb0 = Bt + (size_t)(n0 + r0_) * K + c0_ * 8;
    const unsigned short* gb1 = Bt + (size_t)(n0 + r1_) * K + c1_ * 8;
    unsigned short* lA0 = &As[(wave * 128) * 8];
    unsigned short* lA1 = &As[(wave * 128 + 64) * 8];
    unsigned short* lB0 = &Bs[(wave * 128) * 8];
    unsigned short* lB1 = &Bs[(wave * 128 + 64) * 8];

    f32x4 acc[4][4];
    #pragma unroll
    for (int i = 0; i < 4; ++i)
        #pragma unroll
        for (int j = 0; j < 4; ++j) acc[i][j] = (f32x4){0.f, 0.f, 0.f, 0.f};

    for (int k0 = 0; k0 < K; k0 += 32) {
        __syncthreads();
        gl_lds16(ga0 + k0, lA0);
        gl_lds16(ga1 + k0, lA1);
        gl_lds16(gb0 + k0, lB0);
        gl_lds16(gb1 + k0, lB1);
        __syncthreads();
        bf16x8 af[4], bfr[4];
        #pragma unroll
        for (int mt = 0; mt < 4; ++mt)
            af[mt] = *(const bf16x8*)&As[(q * 128 + wm + mt * 16 + l16) * 8];
        #pragma unroll
        for (int nt = 0; nt < 4; ++nt)
            bfr[nt] = *(const bf16x8*)&Bs[(q * 128 + wn + nt * 16 + l16) * 8];
        #pragma unroll
        for (int mt = 0; mt < 4; ++mt)
            #pragma unroll
            for (int nt = 0; nt < 4; ++nt)
                acc[mt][nt] = __builtin_amdgcn_mfma_f32_16x16x32_bf16(
                    af[mt], bfr[nt], acc[mt][nt], 0, 0, 0);
    }
    // C/D layout: col = lane&15, row = (lane>>4)*4 + reg
    #pragma unroll
    for (int mt = 0; mt < 4; ++mt)
        #pragma unroll
        for (int r = 0; r < 4; ++r) {
            int grow = m0 + wm + mt * 16 + q * 4 + r;
            #pragma unroll
            for (int nt = 0; nt < 4; ++nt)
                C[(size_t)grow * N + n0 + wn + nt * 16 + l16] = acc[mt][nt][r];
        }
}

// ---------------------------------------------------------------------------
// row-wise l2 normalize (over C=512), in place. 1 wave per row.
// ---------------------------------------------------------------------------
__global__ __launch_bounds__(256) void l2norm_rows(float* __restrict__ q, float* __restrict__ k)
{
    const int row  = blockIdx.x * 4 + (threadIdx.x >> 6);
    const int lane = threadIdx.x & 63;
    float* p = (blockIdx.y ? k : q) + (size_t)row * CC;
    float4* p4 = (float4*)p;
    float4 x0 = p4[lane];
    float4 x1 = p4[lane + 64];
    float ss = dot4(x0, x0) + dot4(x1, x1);
    #pragma unroll
    for (int off = 32; off > 0; off >>= 1) ss += __shfl_xor(ss, off, 64);
    float sc = 1.f / fmaxf(sqrtf(ss), 1e-12f);
    x0.x *= sc; x0.y *= sc; x0.z *= sc; x0.w *= sc;
    x1.x *= sc; x1.y *= sc; x1.z *= sc; x1.w *= sc;
    p4[lane] = x0; p4[lane + 64] = x1;
}

// ---------------------------------------------------------------------------
// per-chunk local states: S_local[bh][c][e][d] = sum_j lam^j k[c0+j][e] v[c0+j][d]
// ---------------------------------------------------------------------------
__global__ __launch_bounds__(256) void state_local(
    const float* __restrict__ k, const float* __restrict__ v,
    const float* __restrict__ dlog, float* __restrict__ states)
{
    __shared__ float ksA[16][132];
    __shared__ float vsA[16][132];
    const int c  = blockIdx.x;
    const int bh = blockIdx.y;
    const int b = bh >> 2, h = bh & 3;
    const float lam = 1.f / (1.f + __expf(-dlog[h]));
    const float l2lam = log2f(lam);
    const int t = threadIdx.x;
    const int tx = t & 15, ty = t >> 4;
    const size_t gbase = ((size_t)(b * TT + c * QC)) * CC + h * DD;

    float acc[8][8] = {};

    for (int j0 = 0; j0 < QC; j0 += 16) {
        __syncthreads();
        #pragma unroll
        for (int s = 0; s < 2; ++s) {
            int f4 = s * 256 + t;
            int r = f4 >> 5, c4 = (f4 & 31) * 4;
            float4 kv = *(const float4*)(k + gbase + (size_t)(j0 + r) * CC + c4);
            float4 vv = *(const float4*)(v + gbase + (size_t)(j0 + r) * CC + c4);
            float w = exp2f((float)(j0 + r) * l2lam);
            kv.x *= w; kv.y *= w; kv.z *= w; kv.w *= w;
            *(float4*)&ksA[r][c4] = kv;
            *(float4*)&vsA[r][c4] = vv;
        }
        __syncthreads();
        #pragma unroll
        for (int jj = 0; jj < 16; ++jj) {
            float4 ka0 = *(const float4*)&ksA[jj][ty * 8];
            float4 ka1 = *(const float4*)&ksA[jj][ty * 8 + 4];
            float4 va0 = *(const float4*)&vsA[jj][tx * 8];
            float4 va1 = *(const float4*)&vsA[jj][tx * 8 + 4];
            float ke[8] = {ka0.x, ka0.y, ka0.z, ka0.w, ka1.x, ka1.y, ka1.z, ka1.w};
            float vd[8] = {va0.x, va0.y, va0.z, va0.w, va1.x, va1.y, va1.z, va1.w};
            #pragma unroll
            for (int a = 0; a < 8; ++a)
                #pragma unroll
                for (int d = 0; d < 8; ++d)
                    acc[a][d] = fmaf(ke[a], vd[d], acc[a][d]);
        }
    }
    float* so = states + ((size_t)(bh * NCH + c) << 14);
    #pragma unroll
    for (int a = 0; a < 8; ++a) {
        float* p = so + (ty * 8 + a) * DD + tx * 8;
        *(float4*)(p + 0) = make_float4(acc[a][0], acc[a][1], acc[a][2], acc[a][3]);
        *(float4*)(p + 4) = make_float4(acc[a][4], acc[a][5], acc[a][6], acc[a][7]);
    }
}

// ---------------------------------------------------------------------------
// suffix combine, parallelized: 256 blocks (16 bh x 16 parts), 1 float4/thread.
// After: states[bh][c] = suffix state usable as cross-state for chunk c.
// ---------------------------------------------------------------------------
__global__ __launch_bounds__(256) void state_combine(
    const float* __restrict__ dlog, float* __restrict__ states)
{
    const int bh = blockIdx.x >> 4, part = blockIdx.x & 15;
    const int h = bh & 3;
    const float lam = 1.f / (1.f + __expf(-dlog[h]));
    const float lamQ = exp2f((float)QC * log2f(lam));
    const int t = threadIdx.x;
    float4 run = make_float4(0.f, 0.f, 0.f, 0.f);
    float4* pbase = (float4*)(states + ((size_t)(bh * NCH) << 14)) + part * 256 + t;
    for (int c = NCH - 1; c >= 0; --c) {
        float4* p = pbase + ((size_t)c << 12);
        float4 tmp = *p;
        *p = run;
        run.x = fmaf(lamQ, run.x, tmp.x);
        run.y = fmaf(lamQ, run.y, tmp.y);
        run.z = fmaf(lamQ, run.z, tmp.z);
        run.w = fmaf(lamQ, run.w, tmp.w);
    }
}

// ---------------------------------------------------------------------------
// fused intra-chunk attention + cross term, writes final retrieved as bf16.
// intra: sum_{j>i, j in chunk} lam^(j-i-1) (q_i.k_j) v_j
// cross: lam^(QC-1-ii) * q_i @ S_chunk   (S staged through ks LDS)
// ---------------------------------------------------------------------------
#define TI 32
#define TJ 32
#define LST 132

__global__ __launch_bounds__(256) void attention_fused(
    const float* __restrict__ q, const float* __restrict__ k,
    const float* __restrict__ v, const float* __restrict__ states,
    const float* __restrict__ dlog, __hip_bfloat16* __restrict__ retb)
{
    __shared__ float qs[TI][LST];
    __shared__ float ks[TJ][LST];
    __shared__ float vs[TJ][LST];
    __shared__ float ss[TI][TJ + 1];

    const int it = blockIdx.x;           // 0..63
    const int bh = blockIdx.y;           // 0..15
    const int b = bh >> 2, h = bh & 3;
    const float lam = 1.f / (1.f + __expf(-dlog[h]));
    const float l2lam = log2f(lam);
    const int i0 = it * TI;
    const int t = threadIdx.x;

    const size_t base = (size_t)(b * TT) * CC + h * DD;
    const float* qbase = q + base;
    const float* kbase = k + base;
    const float* vbase = v + base;

    const int lr = t >> 3;
    const int ld = (t & 7) * 16;
    {
        const float* src = qbase + (size_t)(i0 + lr) * CC + ld;
        #pragma unroll
        for (int i = 0; i < 4; ++i)
            *(float4*)&qs[lr][ld + 4 * i] = *(const float4*)(src + 4 * i);
    }

    const int si = t & 15;
    const int sj = t >> 4;
    float4 acc00 = {0,0,0,0}, acc01 = {0,0,0,0};
    float4 acc10 = {0,0,0,0}, acc11 = {0,0,0,0};

    // ---- intra part (verified decay/mask logic) ----
    const int jt_end = 2 * (it >> 1) + 2;
    for (int jt = it; jt < jt_end; ++jt) {
        const int j0 = jt * TJ;
        __syncthreads();
        {
            const float* ksrc = kbase + (size_t)(j0 + lr) * CC + ld;
            const float* vsrc = vbase + (size_t)(j0 + lr) * CC + ld;
            #pragma unroll
            for (int i = 0; i < 4; ++i) {
                *(float4*)&ks[lr][ld + 4 * i] = *(const float4*)(ksrc + 4 * i);
                *(float4*)&vs[lr][ld + 4 * i] = *(const float4*)(vsrc + 4 * i);
            }
        }
        __syncthreads();
        float s00 = 0.f, s01 = 0.f, s10 = 0.f, s11 = 0.f;
        #pragma unroll 8
        for (int d4 = 0; d4 < DD / 4; ++d4) {
            float4 q0 = *(const float4*)&qs[si * 2 + 0][d4 * 4];
            float4 q1 = *(const float4*)&qs[si * 2 + 1][d4 * 4];
            float4 k0 = *(const float4*)&ks[sj * 2 + 0][d4 * 4];
            float4 k1 = *(const float4*)&ks[sj * 2 + 1][d4 * 4];
            s00 += dot4(q0, k0); s01 += dot4(q0, k1);
            s10 += dot4(q1, k0); s11 += dot4(q1, k1);
        }
        const int di = (j0 + sj * 2) - (i0 + si * 2);
        const float w_m1 = exp2f((float)(di - 1) * l2lam);
        const float w_0  = exp2f((float)(di)     * l2lam);
        const float w_m2 = exp2f((float)(di - 2) * l2lam);
        ss[si*2+0][sj*2+0] = (di > 0)  ? s00 * w_m1 : 0.f;
        ss[si*2+0][sj*2+1] = (di >= 0) ? s01 * w_0  : 0.f;
        ss[si*2+1][sj*2+0] = (di > 1)  ? s10 * w_m2 : 0.f;
        ss[si*2+1][sj*2+1] = (di > 0)  ? s11 * w_m1 : 0.f;
        __syncthreads();
        #pragma unroll 8
        for (int j = 0; j < TJ; ++j) {
            float w0 = ss[si * 2 + 0][j];
            float w1 = ss[si * 2 + 1][j];
            float4 v0 = *(const float4*)&vs[j][sj * 8 + 0];
            float4 v1 = *(const float4*)&vs[j][sj * 8 + 4];
            fma4(acc00, w0, v0); fma4(acc01, w0, v1);
            fma4(acc10, w1, v0); fma4(acc11, w1, v1);
        }
    }

    // ---- cross part: cacc = q_i @ S (S = states[bh][it>>1], 128x128) ----
    float4 cacc00 = {0,0,0,0}, cacc01 = {0,0,0,0};
    float4 cacc10 = {0,0,0,0}, cacc11 = {0,0,0,0};
    const float* sp = states + ((size_t)(bh * NCH + (it >> 1)) << 14);
    __syncthreads();   // all threads done reading ks from intra
    for (int et = 0; et < 4; ++et) {
        #pragma unroll
        for (int s = 0; s < 4; ++s) {
            int f4 = s * 256 + t;
            int r = f4 >> 5, c4 = (f4 & 31) * 4;
            *(float4*)&ks[r][c4] = *(const float4*)(sp + (et * 32 + r) * DD + c4);
        }
        __syncthreads();
        #pragma unroll 8
        for (int e = 0; e < 32; ++e) {
            float q0 = qs[si * 2 + 0][et * 32 + e];
            float q1 = qs[si * 2 + 1][et * 32 + e];
            float4 s0 = *(const float4*)&ks[e][sj * 8 + 0];
            float4 s1 = *(const float4*)&ks[e][sj * 8 + 4];
            fma4(cacc00, q0, s0); fma4(cacc01, q0, s1);
            fma4(cacc10, q1, s0); fma4(cacc11, q1, s1);
        }
        __syncthreads();
    }

    // ---- combine + bf16 store ----
    const int iiA = (it & 1) * 32 + si * 2;   // in-chunk row index
    const float wA = exp2f((float)(QC - 1 - iiA) * l2lam);
    const float wB = exp2f((float)(QC - 2 - iiA) * l2lam);
    float4 tA0 = make_float4(acc00.x + wA * cacc00.x, acc00.y + wA * cacc00.y,
                             acc00.z + wA * cacc00.z, acc00.w + wA * cacc00.w);
    float4 tA1 = make_float4(acc01.x + wA * cacc01.x, acc01.y + wA * cacc01.y,
                             acc01.z + wA * cacc01.z, acc01.w + wA * cacc01.w);
    float4 tB0 = make_float4(acc10.x + wB * cacc10.x, acc10.y + wB * cacc10.y,
                             acc10.z + wB * cacc10.z, acc10.w + wB * cacc10.w);
    float4 tB1 = make_float4(acc11.x + wB * cacc11.x, acc11.y + wB * cacc11.y,
                             acc11.z + wB * cacc11.z, acc11.w + wB * cacc11.w);
    __hip_bfloat16* r0 = retb + (size_t)(b * TT + i0 + si * 2 + 0) * CC + h * DD + sj * 8;
    __hip_bfloat16* r1 = retb + (size_t)(b * TT + i0 + si * 2 + 1) * CC + h * DD + sj * 8;
    store_bf16x8(r0, tA0, tA1);
    store_bf16x8(r1, tB0, tB1);
}

// ---------------------------------------------------------------------------
extern "C" void kernel_launch(void* const* d_in, const int* in_sizes, int n_in,
                              void* d_out, int out_size, void* d_ws, size_t ws_size,
                              hipStream_t stream) {
    const float* x         = (const float*)d_in[0];
    const float* basis     = (const float*)d_in[1];
    const float* qw        = (const float*)d_in[2];
    const float* kw        = (const float*)d_in[3];
    const float* v_coeffs  = (const float*)d_in[4];
    const float* o_coeffs  = (const float*)d_in[5];
    const float* dlog      = (const float*)d_in[6];
    const float* out_scale = (const float*)d_in[7];
    float* out             = (float*)d_out;

    float* ws     = (float*)d_ws;
    float* qbuf   = ws;                               // 8192*512 f32
    float* kbuf   = qbuf + (size_t)NROWS * CC;        // 8192*512 f32
    float* vbuf   = kbuf + (size_t)NROWS * CC;        // 8192*512 f32
    float* states = vbuf + (size_t)NROWS * CC;        // 16*32*128*128 f32
    __hip_bfloat16* xb   = (__hip_bfloat16*)(states + ((size_t)BB * HH * NCH) * DD * DD);
    __hip_bfloat16* retb = xb;                        // alias: xb dead after projections
    __hip_bfloat16* qbw  = xb  + (size_t)NROWS * CC;  // 512*512 bf16 (qw^T)
    __hip_bfloat16* kbw  = qbw + (size_t)VV * CC;
    __hip_bfloat16* v_wT = kbw + (size_t)VV * CC;
    __hip_bfloat16* o_ws = v_wT + (size_t)VV * CC;

    // 1. casts / transposes / weight prep
    cvt_bf16<<<NROWS * CC / 4 / 256, 256, 0, stream>>>(x, xb);
    dim3 tgrid(CC / 32, VV / 32);
    transpose_cvt<<<tgrid, 256, 0, stream>>>(qw, qbw);
    transpose_cvt<<<tgrid, 256, 0, stream>>>(kw, kbw);
    prep_weights<<<2 * VV * CC / 256, 256, 0, stream>>>(basis, v_coeffs, o_coeffs,
                                                        out_scale, v_wT, o_ws);
    // 2. projections (bf16 MFMA, fp32 out)
    dim3 ggrid(CC / 128, NROWS / 128);
    gemm_bf16<<<ggrid, 256, 0, stream>>>(xb, qbw,  qbuf, NROWS, CC, VV);
    gemm_bf16<<<ggrid, 256, 0, stream>>>(xb, kbw,  kbuf, NROWS, CC, VV);
    gemm_bf16<<<ggrid, 256, 0, stream>>>(xb, v_wT, vbuf, NROWS, CC, VV);
    // 3. l2norm q,k
    l2norm_rows<<<dim3(NROWS / 4, 2), 256, 0, stream>>>(qbuf, kbuf);
    // 4. chunked linear attention
    state_local  <<<dim3(NCH, BB * HH), 256, 0, stream>>>(kbuf, vbuf, dlog, states);
    state_combine<<<BB * HH * 16, 256, 0, stream>>>(dlog, states);
    attention_fused<<<dim3(TT / TI, BB * HH), 256, 0, stream>>>(qbuf, kbuf, vbuf,
                                                                states, dlog, retb);
    // 5. output projection (o_ws includes out_scale), fp32 out
    gemm_bf16<<<ggrid, 256, 0, stream>>>(retb, o_ws, out, NROWS, VV, CC);
}

// Round 5
// 234.979 us; speedup vs baseline: 4.7922x; 1.2671x over previous
//
#include <hip/hip_runtime.h>
#include <hip/hip_bf16.h>

// Problem constants (fixed by setup_inputs)
#define BB 4
#define TT 2048
#define VV 512
#define CC 512
#define HH 4
#define DD 128
#define NB2 128          // 2*NB
#define NROWS (BB*TT)    // 8192
#define QC 64            // linear-attention chunk length
#define NCH (TT/QC)      // 32 chunks per sequence
#define SST 66           // padded LDS stride (words: 33 -> conflict-free rotation)

typedef __attribute__((ext_vector_type(8))) short bf16x8;
typedef __attribute__((ext_vector_type(4))) float f32x4;

__device__ __forceinline__ float dot4(float4 a, float4 b) {
    return a.x*b.x + a.y*b.y + a.z*b.z + a.w*b.w;
}
__device__ __forceinline__ void gl_lds16(const void* g, void* l) {
    __builtin_amdgcn_global_load_lds(
        (const __attribute__((address_space(1))) unsigned int*)g,
        (__attribute__((address_space(3))) unsigned int*)l, 16, 0, 0);
}
__device__ __forceinline__ unsigned short f2bu(float x) {
    __hip_bfloat16 h = __float2bfloat16(x);
    return *reinterpret_cast<unsigned short*>(&h);
}
__device__ __forceinline__ float bu2f(unsigned short u) {
    __hip_bfloat16 h = *reinterpret_cast<__hip_bfloat16*>(&u);
    return __bfloat162float(h);
}

// ---------------------------------------------------------------------------
// x (fp32) -> xb (bf16)
// ---------------------------------------------------------------------------
__global__ __launch_bounds__(256) void cvt_bf16(
    const float* __restrict__ in, __hip_bfloat16* __restrict__ out)
{
    int i = blockIdx.x * 256 + threadIdx.x;
    float4 v = ((const float4*)in)[i];
    unsigned short h[4] = {f2bu(v.x), f2bu(v.y), f2bu(v.z), f2bu(v.w)};
    ((uint2*)out)[i] = *(uint2*)h;
}

// ---------------------------------------------------------------------------
// 512x512 transpose + convert: outT[c][v] = in[v][c] as bf16
// ---------------------------------------------------------------------------
__global__ __launch_bounds__(256) void transpose_cvt(
    const float* __restrict__ in, __hip_bfloat16* __restrict__ outT)
{
    __shared__ float tile[32][33];
    const int bx = blockIdx.x * 32, by = blockIdx.y * 32;
    const int tx = threadIdx.x & 31, ty = threadIdx.x >> 5;   // 32 x 8
    #pragma unroll
    for (int r = 0; r < 32; r += 8)
        tile[ty + r][tx] = in[(size_t)(by + ty + r) * CC + bx + tx];
    __syncthreads();
    #pragma unroll
    for (int r = 0; r < 32; r += 8)
        outT[(size_t)(bx + ty + r) * VV + by + tx] = __float2bfloat16(tile[tx][ty + r]);
}

// ---------------------------------------------------------------------------
// prep: v_wT[c][v] = (basis @ v_coeffs.T)^T (bf16)  -> wcat section 2
//       o_ws[v][c] = (basis @ o_coeffs.T) * out_scale (bf16)
// ---------------------------------------------------------------------------
__global__ __launch_bounds__(256) void prep_weights(
    const float* __restrict__ basis, const float* __restrict__ v_coeffs,
    const float* __restrict__ o_coeffs, const float* __restrict__ out_scale,
    __hip_bfloat16* __restrict__ v_wT, __hip_bfloat16* __restrict__ o_ws)
{
    int idx = blockIdx.x * 256 + threadIdx.x;
    const int total = VV * CC;
    if (idx < total) {
        int c = idx >> 9, vi = idx & 511;      // v_wT[c][vi]
        const float4* bp = (const float4*)(basis + (size_t)vi * NB2);
        const float4* cp = (const float4*)(v_coeffs + (size_t)c * NB2);
        float s = 0.f;
        #pragma unroll
        for (int n = 0; n < NB2 / 4; ++n) s += dot4(bp[n], cp[n]);
        v_wT[idx] = __float2bfloat16(s);
    } else {
        int idx2 = idx - total;
        int vi = idx2 >> 9, c = idx2 & 511;    // o_ws[vi][c]
        const float4* bp = (const float4*)(basis + (size_t)vi * NB2);
        const float4* cp = (const float4*)(o_coeffs + (size_t)c * NB2);
        float s = 0.f;
        #pragma unroll
        for (int n = 0; n < NB2 / 4; ++n) s += dot4(bp[n], cp[n]);
        o_ws[idx2] = __float2bfloat16(s * out_scale[0]);
    }
}

// ---------------------------------------------------------------------------
// bf16 MFMA GEMM body: C[M,N] fp32 = A[M,K] @ Bt[N,K]^T, 128x128 tile, BK=32.
// (verified in round 4)
// ---------------------------------------------------------------------------
__device__ __forceinline__ void gemm_body(
    const unsigned short* __restrict__ A, const unsigned short* __restrict__ Bt,
    float* __restrict__ C, int M, int N, int K, int m0, int n0,
    unsigned short* As, unsigned short* Bs)
{
    const int t = threadIdx.x;
    const int wave = t >> 6, lane = t & 63;
    const int q = lane >> 4, l16 = lane & 15;
    const int wm = (wave >> 1) * 64, wn = (wave & 1) * 64;

    const int sA0 = wave * 128 + lane, sA1 = sA0 + 64;
    const int r0_ = sA0 & 127, c0_ = sA0 >> 7;
    const int r1_ = sA1 & 127, c1_ = sA1 >> 7;
    const unsigned short* ga0 = A  + (size_t)(m0 + r0_) * K + c0_ * 8;
    const unsigned short* ga1 = A  + (size_t)(m0 + r1_) * K + c1_ * 8;
    const unsigned short* gb0 = Bt + (size_t)(n0 + r0_) * K + c0_ * 8;
    const unsigned short* gb1 = Bt + (size_t)(n0 + r1_) * K + c1_ * 8;
    unsigned short* lA0 = &As[(wave * 128) * 8];
    unsigned short* lA1 = &As[(wave * 128 + 64) * 8];
    unsigned short* lB0 = &Bs[(wave * 128) * 8];
    unsigned short* lB1 = &Bs[(wave * 128 + 64) * 8];

    f32x4 acc[4][4];
    #pragma unroll
    for (int i = 0; i < 4; ++i)
        #pragma unroll
        for (int j = 0; j < 4; ++j) acc[i][j] = (f32x4){0.f, 0.f, 0.f, 0.f};

    for (int k0 = 0; k0 < K; k0 += 32) {
        __syncthreads();
        gl_lds16(ga0 + k0, lA0);
        gl_lds16(ga1 + k0, lA1);
        gl_lds16(gb0 + k0, lB0);
        gl_lds16(gb1 + k0, lB1);
        __syncthreads();
        bf16x8 af[4], bfr[4];
        #pragma unroll
        for (int mt = 0; mt < 4; ++mt)
            af[mt] = *(const bf16x8*)&As[(q * 128 + wm + mt * 16 + l16) * 8];
        #pragma unroll
        for (int nt = 0; nt < 4; ++nt)
            bfr[nt] = *(const bf16x8*)&Bs[(q * 128 + wn + nt * 16 + l16) * 8];
        #pragma unroll
        for (int mt = 0; mt < 4; ++mt)
            #pragma unroll
            for (int nt = 0; nt < 4; ++nt)
                acc[mt][nt] = __builtin_amdgcn_mfma_f32_16x16x32_bf16(
                    af[mt], bfr[nt], acc[mt][nt], 0, 0, 0);
    }
    #pragma unroll
    for (int mt = 0; mt < 4; ++mt)
        #pragma unroll
        for (int r = 0; r < 4; ++r) {
            int grow = m0 + wm + mt * 16 + q * 4 + r;
            #pragma unroll
            for (int nt = 0; nt < 4; ++nt)
                C[(size_t)grow * N + n0 + wn + nt * 16 + l16] = acc[mt][nt][r];
        }
}

__global__ __launch_bounds__(256) void gemm_bf16(
    const __hip_bfloat16* __restrict__ Ab, const __hip_bfloat16* __restrict__ Btb,
    float* __restrict__ C, int M, int N, int K)
{
    __shared__ __align__(16) unsigned short As[4096];
    __shared__ __align__(16) unsigned short Bs[4096];
    gemm_body((const unsigned short*)Ab, (const unsigned short*)Btb, C, M, N, K,
              blockIdx.y * 128, blockIdx.x * 128, As, Bs);
}

// merged q/k/v projection: grid (12, 64); section = bx>>2
__global__ __launch_bounds__(256) void gemm_qkv(
    const __hip_bfloat16* __restrict__ xb, const __hip_bfloat16* __restrict__ wcat,
    float* __restrict__ qo, float* __restrict__ ko, float* __restrict__ vo)
{
    __shared__ __align__(16) unsigned short As[4096];
    __shared__ __align__(16) unsigned short Bs[4096];
    const int sec = blockIdx.x >> 2;
    float* outp = sec == 0 ? qo : (sec == 1 ? ko : vo);
    gemm_body((const unsigned short*)xb,
              (const unsigned short*)wcat + (size_t)sec * VV * CC,
              outp, NROWS, CC, VV, blockIdx.y * 128, (blockIdx.x & 3) * 128, As, Bs);
}

// ---------------------------------------------------------------------------
// row-wise l2 normalize (over C=512), in place. 1 wave per row.
// ---------------------------------------------------------------------------
__global__ __launch_bounds__(256) void l2norm_rows(float* __restrict__ q, float* __restrict__ k)
{
    const int row  = blockIdx.x * 4 + (threadIdx.x >> 6);
    const int lane = threadIdx.x & 63;
    float* p = (blockIdx.y ? k : q) + (size_t)row * CC;
    float4* p4 = (float4*)p;
    float4 x0 = p4[lane];
    float4 x1 = p4[lane + 64];
    float ss = dot4(x0, x0) + dot4(x1, x1);
    #pragma unroll
    for (int off = 32; off > 0; off >>= 1) ss += __shfl_xor(ss, off, 64);
    float sc = 1.f / fmaxf(sqrtf(ss), 1e-12f);
    x0.x *= sc; x0.y *= sc; x0.z *= sc; x0.w *= sc;
    x1.x *= sc; x1.y *= sc; x1.z *= sc; x1.w *= sc;
    p4[lane] = x0; p4[lane + 64] = x1;
}

// ---------------------------------------------------------------------------
// per-chunk local states, TRANSPOSED, bf16 out:
// St_local[bh][c][d][e] = sum_{j=0..63} lam^j * v[c0+j][d] * k[c0+j][e]
// ---------------------------------------------------------------------------
__global__ __launch_bounds__(256) void state_local(
    const float* __restrict__ k, const float* __restrict__ v,
    const float* __restrict__ dlog, __hip_bfloat16* __restrict__ statesb)
{
    __shared__ float ksA[16][132];
    __shared__ float vsA[16][132];
    const int c  = blockIdx.x;
    const int bh = blockIdx.y;
    const int b = bh >> 2, h = bh & 3;
    const float lam = 1.f / (1.f + __expf(-dlog[h]));
    const float l2lam = log2f(lam);
    const int t = threadIdx.x;
    const int tx = t & 15, ty = t >> 4;
    const size_t gbase = ((size_t)(b * TT + c * QC)) * CC + h * DD;

    float acc[8][8] = {};

    for (int j0 = 0; j0 < QC; j0 += 16) {
        __syncthreads();
        #pragma unroll
        for (int s = 0; s < 2; ++s) {
            int f4 = s * 256 + t;
            int r = f4 >> 5, c4 = (f4 & 31) * 4;
            float4 kv = *(const float4*)(k + gbase + (size_t)(j0 + r) * CC + c4);
            float4 vv = *(const float4*)(v + gbase + (size_t)(j0 + r) * CC + c4);
            float w = exp2f((float)(j0 + r) * l2lam);
            vv.x *= w; vv.y *= w; vv.z *= w; vv.w *= w;   // scale v by lam^j
            *(float4*)&ksA[r][c4] = kv;
            *(float4*)&vsA[r][c4] = vv;
        }
        __syncthreads();
        #pragma unroll
        for (int jj = 0; jj < 16; ++jj) {
            float4 va0 = *(const float4*)&vsA[jj][ty * 8];
            float4 va1 = *(const float4*)&vsA[jj][ty * 8 + 4];
            float4 ka0 = *(const float4*)&ksA[jj][tx * 8];
            float4 ka1 = *(const float4*)&ksA[jj][tx * 8 + 4];
            float vd[8] = {va0.x, va0.y, va0.z, va0.w, va1.x, va1.y, va1.z, va1.w};
            float ke[8] = {ka0.x, ka0.y, ka0.z, ka0.w, ka1.x, ka1.y, ka1.z, ka1.w};
            #pragma unroll
            for (int a = 0; a < 8; ++a)
                #pragma unroll
                for (int d = 0; d < 8; ++d)
                    acc[a][d] = fmaf(vd[a], ke[d], acc[a][d]);   // [d-dim][e-dim]
        }
    }
    __hip_bfloat16* so = statesb + ((size_t)(bh * NCH + c) << 14);
    #pragma unroll
    for (int a = 0; a < 8; ++a) {
        unsigned short h8[8];
        #pragma unroll
        for (int d = 0; d < 8; ++d) h8[d] = f2bu(acc[a][d]);
        *(uint4*)(so + (size_t)(ty * 8 + a) * DD + tx * 8) = *(uint4*)h8;
    }
}

// ---------------------------------------------------------------------------
// suffix combine in place (bf16 storage, fp32 running state).
// After: statesb[bh][c] = St for chunk c = sum_{j>=(c+1)QC} lam^(j-(c+1)QC) v k^T
// ---------------------------------------------------------------------------
__global__ __launch_bounds__(256) void state_combine(
    const float* __restrict__ dlog, __hip_bfloat16* __restrict__ statesb)
{
    const int bh = blockIdx.x >> 3, part = blockIdx.x & 7;
    const int h = bh & 3;
    const float lam = 1.f / (1.f + __expf(-dlog[h]));
    const float lamQ = exp2f((float)QC * log2f(lam));
    const int t = threadIdx.x;
    float run[8] = {};
    uint4* pbase = (uint4*)(statesb + ((size_t)(bh * NCH) << 14)) + part * 256 + t;
    for (int c = NCH - 1; c >= 0; --c) {
        uint4* p = pbase + (size_t)c * 2048;   // 16384 bf16 / 8 per uint4
        uint4 raw = *p;
        unsigned short* hb = (unsigned short*)&raw;
        uint4 outw;
        unsigned short* ho = (unsigned short*)&outw;
        #pragma unroll
        for (int i = 0; i < 8; ++i) {
            float tmp = bu2f(hb[i]);
            ho[i] = f2bu(run[i]);
            run[i] = fmaf(lamQ, run[i], tmp);
        }
        *p = outw;
    }
}

// ---------------------------------------------------------------------------
// fused MFMA attention: one block per (chunk, bh). 4 waves x 16 rows.
// intra: P = mask/decay(q k^T) ; ret = P @ V  (P via LDS, bf16)
// cross: ret += diag(lam^(63-ii)) q @ St^T    (St bf16, direct global B-frags)
// writes final retrieved bf16.
// ---------------------------------------------------------------------------
__global__ __launch_bounds__(256) void attention_fused(
    const float* __restrict__ q, const float* __restrict__ k,
    const float* __restrict__ v, const __hip_bfloat16* __restrict__ statesb,
    const float* __restrict__ dlog, __hip_bfloat16* __restrict__ retb)
{
    __shared__ __align__(16) unsigned short qs[QC][DD];
    __shared__ __align__(16) unsigned short ks[QC][DD];
    __shared__ __align__(16) unsigned short vsT[DD][SST];
    __shared__ __align__(16) unsigned short ss[QC][SST];

    const int c = blockIdx.x, bh = blockIdx.y;
    const int b = bh >> 2, h = bh & 3;
    const float lam = 1.f / (1.f + __expf(-dlog[h]));
    const float l2lam = log2f(lam);
    const int t = threadIdx.x;
    const size_t base = ((size_t)(b * TT + c * QC)) * CC + h * DD;

    // ---- stage q,k -> bf16 LDS [row][e] ----
    {
        const int row = t >> 2, cs = (t & 3) * 32;
        const float* qsrc = q + base + (size_t)row * CC + cs;
        const float* ksrc = k + base + (size_t)row * CC + cs;
        #pragma unroll
        for (int u = 0; u < 4; ++u) {
            float4 a0 = *(const float4*)(qsrc + u * 8);
            float4 a1 = *(const float4*)(qsrc + u * 8 + 4);
            unsigned short h8[8] = {f2bu(a0.x), f2bu(a0.y), f2bu(a0.z), f2bu(a0.w),
                                    f2bu(a1.x), f2bu(a1.y), f2bu(a1.z), f2bu(a1.w)};
            *(uint4*)&qs[row][cs + u * 8] = *(uint4*)h8;
            float4 b0 = *(const float4*)(ksrc + u * 8);
            float4 b1 = *(const float4*)(ksrc + u * 8 + 4);
            unsigned short g8[8] = {f2bu(b0.x), f2bu(b0.y), f2bu(b0.z), f2bu(b0.w),
                                    f2bu(b1.x), f2bu(b1.y), f2bu(b1.z), f2bu(b1.w)};
            *(uint4*)&ks[row][cs + u * 8] = *(uint4*)g8;
        }
    }
    // ---- stage v transposed -> vsT[d][j] (paired u32 writes, conflict-free) ----
    {
        const int j2 = t & 31, d0 = (t >> 5) * 16;
        const float* v0 = v + base + (size_t)(2 * j2) * CC + d0;
        const float* v1 = v0 + CC;
        #pragma unroll
        for (int u = 0; u < 4; ++u) {
            float4 a = *(const float4*)(v0 + u * 4);
            float4 bb = *(const float4*)(v1 + u * 4);
            const float av[4] = {a.x, a.y, a.z, a.w};
            const float bv[4] = {bb.x, bb.y, bb.z, bb.w};
            #pragma unroll
            for (int i2 = 0; i2 < 4; ++i2) {
                unsigned int w = (unsigned int)f2bu(av[i2]) |
                                 ((unsigned int)f2bu(bv[i2]) << 16);
                *(unsigned int*)&vsT[d0 + u * 4 + i2][2 * j2] = w;
            }
        }
    }
    __syncthreads();   // the only barrier

    const int wave = t >> 6, lane = t & 63;
    const int quad = lane >> 4, l16 = lane & 15;
    const int r0 = wave * 16;   // this wave's 16 query rows

    // A fragments (q rows r0+l16, k=e)
    bf16x8 aq[4];
    #pragma unroll
    for (int kq = 0; kq < 4; ++kq)
        aq[kq] = *(const bf16x8*)&qs[r0 + l16][kq * 32 + quad * 8];

    // ---- scores: 4 j-tiles, K=128 ----
    f32x4 accs[4];
    #pragma unroll
    for (int nt = 0; nt < 4; ++nt) accs[nt] = (f32x4){0.f, 0.f, 0.f, 0.f};
    #pragma unroll
    for (int nt = 0; nt < 4; ++nt)
        #pragma unroll
        for (int kq = 0; kq < 4; ++kq) {
            bf16x8 bk = *(const bf16x8*)&ks[nt * 16 + l16][kq * 32 + quad * 8];
            accs[nt] = __builtin_amdgcn_mfma_f32_16x16x32_bf16(aq[kq], bk, accs[nt], 0, 0, 0);
        }

    // ---- decay + mask -> P (bf16, own rows only) ----
    #pragma unroll
    for (int nt = 0; nt < 4; ++nt) {
        const int j = nt * 16 + l16;
        #pragma unroll
        for (int rr = 0; rr < 4; ++rr) {
            const int i = r0 + quad * 4 + rr;
            const int di = j - i;
            float p = (di > 0) ? accs[nt][rr] * exp2f((float)(di - 1) * l2lam) : 0.f;
            ss[i][j] = f2bu(p);
        }
    }

    // ---- cross: q @ St^T (B-frags straight from global bf16) ----
    const __hip_bfloat16* sb = statesb + ((size_t)(bh * NCH + c) << 14);
    f32x4 accc[8];
    #pragma unroll
    for (int nt = 0; nt < 8; ++nt) accc[nt] = (f32x4){0.f, 0.f, 0.f, 0.f};
    #pragma unroll
    for (int nt = 0; nt < 8; ++nt)
        #pragma unroll
        for (int kq = 0; kq < 4; ++kq) {
            bf16x8 bs_ = *(const bf16x8*)(sb + (size_t)(nt * 16 + l16) * DD + kq * 32 + quad * 8);
            accc[nt] = __builtin_amdgcn_mfma_f32_16x16x32_bf16(aq[kq], bs_, accc[nt], 0, 0, 0);
        }

    // ---- P @ V ----
    bf16x8 ap[2];
    #pragma unroll
    for (int kj = 0; kj < 2; ++kj)
        ap[kj] = *(const bf16x8*)&ss[r0 + l16][kj * 32 + quad * 8];
    f32x4 accd[8];
    #pragma unroll
    for (int nt = 0; nt < 8; ++nt) accd[nt] = (f32x4){0.f, 0.f, 0.f, 0.f};
    #pragma unroll
    for (int nt = 0; nt < 8; ++nt)
        #pragma unroll
        for (int kj = 0; kj < 2; ++kj) {
            bf16x8 bv = *(const bf16x8*)&vsT[nt * 16 + l16][kj * 32 + quad * 8];
            accd[nt] = __builtin_amdgcn_mfma_f32_16x16x32_bf16(ap[kj], bv, accd[nt], 0, 0, 0);
        }

    // ---- combine + bf16 store ----
    __hip_bfloat16* rb = retb + ((size_t)(b * TT + c * QC)) * CC + h * DD;
    #pragma unroll
    for (int rr = 0; rr < 4; ++rr) {
        const int ii = r0 + quad * 4 + rr;
        const float wrow = exp2f((float)(QC - 1 - ii) * l2lam);
        #pragma unroll
        for (int nt = 0; nt < 8; ++nt) {
            float val = accd[nt][rr] + wrow * accc[nt][rr];
            rb[(size_t)ii * CC + nt * 16 + l16] = __float2bfloat16(val);
        }
    }
}

// ---------------------------------------------------------------------------
extern "C" void kernel_launch(void* const* d_in, const int* in_sizes, int n_in,
                              void* d_out, int out_size, void* d_ws, size_t ws_size,
                              hipStream_t stream) {
    const float* x         = (const float*)d_in[0];
    const float* basis     = (const float*)d_in[1];
    const float* qw        = (const float*)d_in[2];
    const float* kw        = (const float*)d_in[3];
    const float* v_coeffs  = (const float*)d_in[4];
    const float* o_coeffs  = (const float*)d_in[5];
    const float* dlog      = (const float*)d_in[6];
    const float* out_scale = (const float*)d_in[7];
    float* out             = (float*)d_out;

    float* ws   = (float*)d_ws;
    float* qbuf = ws;                              // 8192*512 f32
    float* kbuf = qbuf + (size_t)NROWS * CC;
    float* vbuf = kbuf + (size_t)NROWS * CC;
    __hip_bfloat16* statesb = (__hip_bfloat16*)(vbuf + (size_t)NROWS * CC); // 16*32*16384 bf16
    __hip_bfloat16* xb   = statesb + (size_t)BB * HH * NCH * DD * DD;
    __hip_bfloat16* retb = xb;                     // alias: xb dead after projections
    __hip_bfloat16* wcat = xb + (size_t)NROWS * CC;   // 3 x 512x512 bf16 (q^T,k^T,v_w^T)
    __hip_bfloat16* o_ws = wcat + 3 * (size_t)VV * CC;

    // 1. casts / transposes / weight prep
    cvt_bf16<<<NROWS * CC / 4 / 256, 256, 0, stream>>>(x, xb);
    dim3 tgrid(CC / 32, VV / 32);
    transpose_cvt<<<tgrid, 256, 0, stream>>>(qw, wcat);
    transpose_cvt<<<tgrid, 256, 0, stream>>>(kw, wcat + (size_t)VV * CC);
    prep_weights<<<2 * VV * CC / 256, 256, 0, stream>>>(
        basis, v_coeffs, o_coeffs, out_scale, wcat + 2 * (size_t)VV * CC, o_ws);
    // 2. merged q/k/v projection
    gemm_qkv<<<dim3(12, NROWS / 128), 256, 0, stream>>>(xb, wcat, qbuf, kbuf, vbuf);
    // 3. l2norm q,k
    l2norm_rows<<<dim3(NROWS / 4, 2), 256, 0, stream>>>(qbuf, kbuf);
    // 4. chunked linear attention (all-MFMA)
    state_local  <<<dim3(NCH, BB * HH), 256, 0, stream>>>(kbuf, vbuf, dlog, statesb);
    state_combine<<<BB * HH * 8, 256, 0, stream>>>(dlog, statesb);
    attention_fused<<<dim3(NCH, BB * HH), 256, 0, stream>>>(qbuf, kbuf, vbuf,
                                                            statesb, dlog, retb);
    // 5. output projection (o_ws includes out_scale)
    gemm_bf16<<<dim3(CC / 128, NROWS / 128), 256, 0, stream>>>(retb, o_ws, out,
                                                               NROWS, VV, CC);
}

// Round 6
// 213.867 us; speedup vs baseline: 5.2653x; 1.0987x over previous
//
#include <hip/hip_runtime.h>
#include <hip/hip_bf16.h>

// Problem constants (fixed by setup_inputs)
#define BB 4
#define TT 2048
#define VV 512
#define CC 512
#define HH 4
#define DD 128
#define NB2 128          // 2*NB
#define NROWS (BB*TT)    // 8192
#define QC 64            // linear-attention chunk length
#define NCH (TT/QC)      // 32 chunks per sequence
#define SST 66           // padded LDS stride (ushorts; 33 words -> conflict-free)

typedef __attribute__((ext_vector_type(8))) short bf16x8;
typedef __attribute__((ext_vector_type(4))) float f32x4;
typedef unsigned short u16;

__device__ __forceinline__ float dot4(float4 a, float4 b) {
    return a.x*b.x + a.y*b.y + a.z*b.z + a.w*b.w;
}
__device__ __forceinline__ void gl_lds16(const void* g, void* l) {
    __builtin_amdgcn_global_load_lds(
        (const __attribute__((address_space(1))) unsigned int*)g,
        (__attribute__((address_space(3))) unsigned int*)l, 16, 0, 0);
}
__device__ __forceinline__ u16 f2bu(float x) {
    __hip_bfloat16 h = __float2bfloat16(x);
    return *reinterpret_cast<u16*>(&h);
}
__device__ __forceinline__ float bu2f(u16 u) {
    __hip_bfloat16 h = *reinterpret_cast<__hip_bfloat16*>(&u);
    return __bfloat162float(h);
}

// ---------------------------------------------------------------------------
// x (fp32) -> xb (bf16)
// ---------------------------------------------------------------------------
__global__ __launch_bounds__(256) void cvt_bf16(
    const float* __restrict__ in, u16* __restrict__ out)
{
    int i = blockIdx.x * 256 + threadIdx.x;
    float4 v = ((const float4*)in)[i];
    u16 h[4] = {f2bu(v.x), f2bu(v.y), f2bu(v.z), f2bu(v.w)};
    ((uint2*)out)[i] = *(uint2*)h;
}

// ---------------------------------------------------------------------------
// 512x512 transpose + convert for qw and kw in one launch (grid.z = 2)
// ---------------------------------------------------------------------------
__global__ __launch_bounds__(256) void transpose_cvt2(
    const float* __restrict__ qw, const float* __restrict__ kw,
    u16* __restrict__ outq, u16* __restrict__ outk)
{
    __shared__ float tile[32][33];
    const float* in = blockIdx.z ? kw : qw;
    u16* outT = blockIdx.z ? outk : outq;
    const int bx = blockIdx.x * 32, by = blockIdx.y * 32;
    const int tx = threadIdx.x & 31, ty = threadIdx.x >> 5;   // 32 x 8
    #pragma unroll
    for (int r = 0; r < 32; r += 8)
        tile[ty + r][tx] = in[(size_t)(by + ty + r) * CC + bx + tx];
    __syncthreads();
    #pragma unroll
    for (int r = 0; r < 32; r += 8)
        outT[(size_t)(bx + ty + r) * VV + by + tx] = f2bu(tile[tx][ty + r]);
}

// ---------------------------------------------------------------------------
// prep: v_wT[c][v] (bf16) -> wcat section 2 ; o_ws[v][c] = o_w * out_scale (bf16)
// ---------------------------------------------------------------------------
__global__ __launch_bounds__(256) void prep_weights(
    const float* __restrict__ basis, const float* __restrict__ v_coeffs,
    const float* __restrict__ o_coeffs, const float* __restrict__ out_scale,
    u16* __restrict__ v_wT, u16* __restrict__ o_ws)
{
    int idx = blockIdx.x * 256 + threadIdx.x;
    const int total = VV * CC;
    if (idx < total) {
        int c = idx >> 9, vi = idx & 511;      // v_wT[c][vi]
        const float4* bp = (const float4*)(basis + (size_t)vi * NB2);
        const float4* cp = (const float4*)(v_coeffs + (size_t)c * NB2);
        float s = 0.f;
        #pragma unroll
        for (int n = 0; n < NB2 / 4; ++n) s += dot4(bp[n], cp[n]);
        v_wT[idx] = f2bu(s);
    } else {
        int idx2 = idx - total;
        int vi = idx2 >> 9, c = idx2 & 511;    // o_ws[vi][c]
        const float4* bp = (const float4*)(basis + (size_t)vi * NB2);
        const float4* cp = (const float4*)(o_coeffs + (size_t)c * NB2);
        float s = 0.f;
        #pragma unroll
        for (int n = 0; n < NB2 / 4; ++n) s += dot4(bp[n], cp[n]);
        o_ws[idx2] = f2bu(s * out_scale[0]);
    }
}

// ---------------------------------------------------------------------------
// bf16 MFMA GEMM body, DOUBLE-BUFFERED LDS (prefetch distance 1).
// C[M,N] = A[M,K] @ Bt[N,K]^T, 128x128 tile, BK=32. Output fp32 or bf16.
// As/Bs are 2*4096 ushorts each (two 16KB-combined buffers).
// ---------------------------------------------------------------------------
template <bool BF16OUT>
__device__ __forceinline__ void gemm_body(
    const u16* __restrict__ A, const u16* __restrict__ Bt,
    void* __restrict__ Cp, int M, int N, int K, int m0, int n0,
    u16* __restrict__ As, u16* __restrict__ Bs)
{
    const int t = threadIdx.x;
    const int wave = t >> 6, lane = t & 63;
    const int qq = lane >> 4, l16 = lane & 15;
    const int wm = (wave >> 1) * 64, wn = (wave & 1) * 64;

    const int sA0 = wave * 128 + lane, sA1 = sA0 + 64;
    const int r0_ = sA0 & 127, c0_ = sA0 >> 7;
    const int r1_ = sA1 & 127, c1_ = sA1 >> 7;
    const u16* ga0 = A  + (size_t)(m0 + r0_) * K + c0_ * 8;
    const u16* ga1 = A  + (size_t)(m0 + r1_) * K + c1_ * 8;
    const u16* gb0 = Bt + (size_t)(n0 + r0_) * K + c0_ * 8;
    const u16* gb1 = Bt + (size_t)(n0 + r1_) * K + c1_ * 8;
    const int lo0 = (wave * 128) * 8, lo1 = (wave * 128 + 64) * 8;

    // prologue: first tile -> buffer 0
    gl_lds16(ga0, As + lo0);
    gl_lds16(ga1, As + lo1);
    gl_lds16(gb0, Bs + lo0);
    gl_lds16(gb1, Bs + lo1);

    f32x4 acc[4][4];
    #pragma unroll
    for (int i = 0; i < 4; ++i)
        #pragma unroll
        for (int j = 0; j < 4; ++j) acc[i][j] = (f32x4){0.f, 0.f, 0.f, 0.f};

    int ib = 0;
    for (int k0 = 0; k0 < K; k0 += 32, ib ^= 1) {
        __syncthreads();   // drains vmcnt: buf[ib] ready; prior reads of buf[ib^1] done
        if (k0 + 32 < K) {
            const int off = (ib ^ 1) * 4096;
            gl_lds16(ga0 + k0 + 32, As + off + lo0);
            gl_lds16(ga1 + k0 + 32, As + off + lo1);
            gl_lds16(gb0 + k0 + 32, Bs + off + lo0);
            gl_lds16(gb1 + k0 + 32, Bs + off + lo1);
        }
        const u16* Ac = As + ib * 4096;
        const u16* Bc = Bs + ib * 4096;
        bf16x8 af[4], bfr[4];
        #pragma unroll
        for (int mt = 0; mt < 4; ++mt)
            af[mt] = *(const bf16x8*)&Ac[(qq * 128 + wm + mt * 16 + l16) * 8];
        #pragma unroll
        for (int nt = 0; nt < 4; ++nt)
            bfr[nt] = *(const bf16x8*)&Bc[(qq * 128 + wn + nt * 16 + l16) * 8];
        #pragma unroll
        for (int mt = 0; mt < 4; ++mt)
            #pragma unroll
            for (int nt = 0; nt < 4; ++nt)
                acc[mt][nt] = __builtin_amdgcn_mfma_f32_16x16x32_bf16(
                    af[mt], bfr[nt], acc[mt][nt], 0, 0, 0);
    }
    // C/D layout: col = lane&15, row = (lane>>4)*4 + reg
    #pragma unroll
    for (int mt = 0; mt < 4; ++mt)
        #pragma unroll
        for (int r = 0; r < 4; ++r) {
            int grow = m0 + wm + mt * 16 + qq * 4 + r;
            #pragma unroll
            for (int nt = 0; nt < 4; ++nt) {
                int gcol = n0 + wn + nt * 16 + l16;
                if (BF16OUT)
                    ((u16*)Cp)[(size_t)grow * N + gcol] = f2bu(acc[mt][nt][r]);
                else
                    ((float*)Cp)[(size_t)grow * N + gcol] = acc[mt][nt][r];
            }
        }
}

// merged q/k/v projection: grid (12, 64); section = bx>>2; bf16 output
__global__ __launch_bounds__(256) void gemm_qkv(
    const u16* __restrict__ xb, const u16* __restrict__ wcat,
    u16* __restrict__ qo, u16* __restrict__ ko, u16* __restrict__ vo)
{
    __shared__ __align__(16) u16 As[8192];
    __shared__ __align__(16) u16 Bs[8192];
    const int sec = blockIdx.x >> 2;
    u16* outp = sec == 0 ? qo : (sec == 1 ? ko : vo);
    gemm_body<true>(xb, wcat + (size_t)sec * VV * CC, outp,
                    NROWS, CC, VV, blockIdx.y * 128, (blockIdx.x & 3) * 128, As, Bs);
}

// final output projection: fp32 out
__global__ __launch_bounds__(256) void gemm_out(
    const u16* __restrict__ Ab, const u16* __restrict__ Btb, float* __restrict__ C)
{
    __shared__ __align__(16) u16 As[8192];
    __shared__ __align__(16) u16 Bs[8192];
    gemm_body<false>(Ab, Btb, C, NROWS, VV, CC,
                     blockIdx.y * 128, blockIdx.x * 128, As, Bs);
}

// ---------------------------------------------------------------------------
// row-wise l2 normalize over C=512, bf16 in place. 1 wave per row.
// ---------------------------------------------------------------------------
__global__ __launch_bounds__(256) void l2norm_bf16(u16* __restrict__ q, u16* __restrict__ k)
{
    const int row  = blockIdx.x * 4 + (threadIdx.x >> 6);
    const int lane = threadIdx.x & 63;
    u16* p = (blockIdx.y ? k : q) + (size_t)row * CC;
    uint4 raw = ((uint4*)p)[lane];           // 8 bf16
    u16* hb = (u16*)&raw;
    float f[8];
    float ss = 0.f;
    #pragma unroll
    for (int i = 0; i < 8; ++i) { f[i] = bu2f(hb[i]); ss += f[i] * f[i]; }
    #pragma unroll
    for (int off = 32; off > 0; off >>= 1) ss += __shfl_xor(ss, off, 64);
    float sc = 1.f / fmaxf(sqrtf(ss), 1e-12f);
    #pragma unroll
    for (int i = 0; i < 8; ++i) hb[i] = f2bu(f[i] * sc);
    ((uint4*)p)[lane] = raw;
}

// ---------------------------------------------------------------------------
// per-chunk local states, TRANSPOSED, bf16 in/out:
// St_local[bh][c][d][e] = sum_{j=0..63} lam^j * v[c0+j][d] * k[c0+j][e]
// ---------------------------------------------------------------------------
__global__ __launch_bounds__(256) void state_local(
    const u16* __restrict__ kb, const u16* __restrict__ vb,
    const float* __restrict__ dlog, u16* __restrict__ statesb)
{
    __shared__ float ksA[16][132];
    __shared__ float vsA[16][132];
    const int c  = blockIdx.x;
    const int bh = blockIdx.y;
    const int b = bh >> 2, h = bh & 3;
    const float lam = 1.f / (1.f + __expf(-dlog[h]));
    const float l2lam = log2f(lam);
    const int t = threadIdx.x;
    const int tx = t & 15, ty = t >> 4;
    const size_t gbase = ((size_t)(b * TT + c * QC)) * CC + h * DD;

    float acc[8][8] = {};

    for (int j0 = 0; j0 < QC; j0 += 16) {
        __syncthreads();
        {
            const int r = t >> 4, c8 = (t & 15) * 8;
            uint4 kraw = *(const uint4*)(kb + gbase + (size_t)(j0 + r) * CC + c8);
            uint4 vraw = *(const uint4*)(vb + gbase + (size_t)(j0 + r) * CC + c8);
            const u16* kp = (const u16*)&kraw;
            const u16* vp = (const u16*)&vraw;
            const float w = exp2f((float)(j0 + r) * l2lam);
            *(float4*)&ksA[r][c8]     = make_float4(bu2f(kp[0]), bu2f(kp[1]), bu2f(kp[2]), bu2f(kp[3]));
            *(float4*)&ksA[r][c8 + 4] = make_float4(bu2f(kp[4]), bu2f(kp[5]), bu2f(kp[6]), bu2f(kp[7]));
            *(float4*)&vsA[r][c8]     = make_float4(bu2f(vp[0]) * w, bu2f(vp[1]) * w, bu2f(vp[2]) * w, bu2f(vp[3]) * w);
            *(float4*)&vsA[r][c8 + 4] = make_float4(bu2f(vp[4]) * w, bu2f(vp[5]) * w, bu2f(vp[6]) * w, bu2f(vp[7]) * w);
        }
        __syncthreads();
        #pragma unroll
        for (int jj = 0; jj < 16; ++jj) {
            float4 va0 = *(const float4*)&vsA[jj][ty * 8];
            float4 va1 = *(const float4*)&vsA[jj][ty * 8 + 4];
            float4 ka0 = *(const float4*)&ksA[jj][tx * 8];
            float4 ka1 = *(const float4*)&ksA[jj][tx * 8 + 4];
            float vd[8] = {va0.x, va0.y, va0.z, va0.w, va1.x, va1.y, va1.z, va1.w};
            float ke[8] = {ka0.x, ka0.y, ka0.z, ka0.w, ka1.x, ka1.y, ka1.z, ka1.w};
            #pragma unroll
            for (int a = 0; a < 8; ++a)
                #pragma unroll
                for (int d = 0; d < 8; ++d)
                    acc[a][d] = fmaf(vd[a], ke[d], acc[a][d]);   // [d-dim][e-dim]
        }
    }
    u16* so = statesb + ((size_t)(bh * NCH + c) << 14);
    #pragma unroll
    for (int a = 0; a < 8; ++a) {
        u16 h8[8];
        #pragma unroll
        for (int d = 0; d < 8; ++d) h8[d] = f2bu(acc[a][d]);
        *(uint4*)(so + (size_t)(ty * 8 + a) * DD + tx * 8) = *(uint4*)h8;
    }
}

// ---------------------------------------------------------------------------
// suffix combine in place (bf16 storage, fp32 running state).
// ---------------------------------------------------------------------------
__global__ __launch_bounds__(256) void state_combine(
    const float* __restrict__ dlog, u16* __restrict__ statesb)
{
    const int bh = blockIdx.x >> 3, part = blockIdx.x & 7;
    const int h = bh & 3;
    const float lam = 1.f / (1.f + __expf(-dlog[h]));
    const float lamQ = exp2f((float)QC * log2f(lam));
    const int t = threadIdx.x;
    float run[8] = {};
    uint4* pbase = (uint4*)(statesb + ((size_t)(bh * NCH) << 14)) + part * 256 + t;
    for (int c = NCH - 1; c >= 0; --c) {
        uint4* p = pbase + (size_t)c * 2048;
        uint4 raw = *p;
        u16* hb = (u16*)&raw;
        uint4 outw;
        u16* ho = (u16*)&outw;
        #pragma unroll
        for (int i = 0; i < 8; ++i) {
            float tmp = bu2f(hb[i]);
            ho[i] = f2bu(run[i]);
            run[i] = fmaf(lamQ, run[i], tmp);
        }
        *p = outw;
    }
}

// ---------------------------------------------------------------------------
// fused MFMA attention (bf16 inputs): one block per (chunk, bh).
// ---------------------------------------------------------------------------
__global__ __launch_bounds__(256) void attention_fused(
    const u16* __restrict__ qb, const u16* __restrict__ kb,
    const u16* __restrict__ vb, const u16* __restrict__ statesb,
    const float* __restrict__ dlog, u16* __restrict__ retb)
{
    __shared__ __align__(16) u16 qs[QC][DD];
    __shared__ __align__(16) u16 ks[QC][DD];
    __shared__ __align__(16) u16 vsT[DD][SST];
    __shared__ __align__(16) u16 ss[QC][SST];

    const int c = blockIdx.x, bh = blockIdx.y;
    const int b = bh >> 2, h = bh & 3;
    const float lam = 1.f / (1.f + __expf(-dlog[h]));
    const float l2lam = log2f(lam);
    const int t = threadIdx.x;
    const size_t base = ((size_t)(b * TT + c * QC)) * CC + h * DD;

    const int wave = t >> 6, lane = t & 63;
    const int quad = lane >> 4, l16 = lane & 15;
    const int r0 = wave * 16;

    // ---- stage q,k via global_load_lds (4 rows per instr per wave) ----
    {
        const int lrow = lane >> 4;              // 0..3
        const int lcol = (lane & 15) * 8;        // elements
        #pragma unroll
        for (int u = 0; u < 4; ++u) {
            const int r = wave * 16 + u * 4;
            gl_lds16(qb + base + (size_t)(r + lrow) * CC + lcol, &qs[r][0]);
            gl_lds16(kb + base + (size_t)(r + lrow) * CC + lcol, &ks[r][0]);
        }
    }
    // ---- stage v transposed -> vsT[d][j] (paired u32 writes, conflict-free) ----
    {
        const int j2 = t & 31, d0 = (t >> 5) * 16;
        const u16* v0 = vb + base + (size_t)(2 * j2) * CC + d0;
        const u16* v1 = v0 + CC;
        uint4 a0 = *(const uint4*)v0;
        uint4 a1 = *(const uint4*)(v0 + 8);
        uint4 b0 = *(const uint4*)v1;
        uint4 b1 = *(const uint4*)(v1 + 8);
        const u16* ap0 = (const u16*)&a0; const u16* ap1 = (const u16*)&a1;
        const u16* bp0 = (const u16*)&b0; const u16* bp1 = (const u16*)&b1;
        #pragma unroll
        for (int i = 0; i < 8; ++i) {
            *(unsigned int*)&vsT[d0 + i][2 * j2] =
                (unsigned int)ap0[i] | ((unsigned int)bp0[i] << 16);
            *(unsigned int*)&vsT[d0 + 8 + i][2 * j2] =
                (unsigned int)ap1[i] | ((unsigned int)bp1[i] << 16);
        }
    }
    __syncthreads();   // the only barrier (drains gl_lds vmcnt + LDS writes)

    // A fragments (q rows r0+l16)
    bf16x8 aq[4];
    #pragma unroll
    for (int kq = 0; kq < 4; ++kq)
        aq[kq] = *(const bf16x8*)&qs[r0 + l16][kq * 32 + quad * 8];

    // ---- scores: 4 j-tiles, K=128 ----
    f32x4 accs[4];
    #pragma unroll
    for (int nt = 0; nt < 4; ++nt) accs[nt] = (f32x4){0.f, 0.f, 0.f, 0.f};
    #pragma unroll
    for (int nt = 0; nt < 4; ++nt)
        #pragma unroll
        for (int kq = 0; kq < 4; ++kq) {
            bf16x8 bk = *(const bf16x8*)&ks[nt * 16 + l16][kq * 32 + quad * 8];
            accs[nt] = __builtin_amdgcn_mfma_f32_16x16x32_bf16(aq[kq], bk, accs[nt], 0, 0, 0);
        }

    // ---- decay + mask -> P (bf16, own rows only) ----
    #pragma unroll
    for (int nt = 0; nt < 4; ++nt) {
        const int j = nt * 16 + l16;
        #pragma unroll
        for (int rr = 0; rr < 4; ++rr) {
            const int i = r0 + quad * 4 + rr;
            const int di = j - i;
            float p = (di > 0) ? accs[nt][rr] * exp2f((float)(di - 1) * l2lam) : 0.f;
            ss[i][j] = f2bu(p);
        }
    }

    // ---- cross: q @ St^T (B-frags straight from global bf16) ----
    const u16* sb = statesb + ((size_t)(bh * NCH + c) << 14);
    f32x4 accc[8];
    #pragma unroll
    for (int nt = 0; nt < 8; ++nt) accc[nt] = (f32x4){0.f, 0.f, 0.f, 0.f};
    #pragma unroll
    for (int nt = 0; nt < 8; ++nt)
        #pragma unroll
        for (int kq = 0; kq < 4; ++kq) {
            bf16x8 bs_ = *(const bf16x8*)(sb + (size_t)(nt * 16 + l16) * DD + kq * 32 + quad * 8);
            accc[nt] = __builtin_amdgcn_mfma_f32_16x16x32_bf16(aq[kq], bs_, accc[nt], 0, 0, 0);
        }

    // ---- P @ V ----
    bf16x8 ap[2];
    #pragma unroll
    for (int kj = 0; kj < 2; ++kj)
        ap[kj] = *(const bf16x8*)&ss[r0 + l16][kj * 32 + quad * 8];
    f32x4 accd[8];
    #pragma unroll
    for (int nt = 0; nt < 8; ++nt) accd[nt] = (f32x4){0.f, 0.f, 0.f, 0.f};
    #pragma unroll
    for (int nt = 0; nt < 8; ++nt)
        #pragma unroll
        for (int kj = 0; kj < 2; ++kj) {
            bf16x8 bv = *(const bf16x8*)&vsT[nt * 16 + l16][kj * 32 + quad * 8];
            accd[nt] = __builtin_amdgcn_mfma_f32_16x16x32_bf16(ap[kj], bv, accd[nt], 0, 0, 0);
        }

    // ---- combine + bf16 store ----
    u16* rb = retb + ((size_t)(b * TT + c * QC)) * CC + h * DD;
    #pragma unroll
    for (int rr = 0; rr < 4; ++rr) {
        const int ii = r0 + quad * 4 + rr;
        const float wrow = exp2f((float)(QC - 1 - ii) * l2lam);
        #pragma unroll
        for (int nt = 0; nt < 8; ++nt) {
            float val = accd[nt][rr] + wrow * accc[nt][rr];
            rb[(size_t)ii * CC + nt * 16 + l16] = f2bu(val);
        }
    }
}

// ---------------------------------------------------------------------------
extern "C" void kernel_launch(void* const* d_in, const int* in_sizes, int n_in,
                              void* d_out, int out_size, void* d_ws, size_t ws_size,
                              hipStream_t stream) {
    const float* x         = (const float*)d_in[0];
    const float* basis     = (const float*)d_in[1];
    const float* qw        = (const float*)d_in[2];
    const float* kw        = (const float*)d_in[3];
    const float* v_coeffs  = (const float*)d_in[4];
    const float* o_coeffs  = (const float*)d_in[5];
    const float* dlog      = (const float*)d_in[6];
    const float* out_scale = (const float*)d_in[7];
    float* out             = (float*)d_out;

    u16* p = (u16*)d_ws;
    u16* qb      = p;                                   // 8192*512 bf16
    u16* kb      = qb + (size_t)NROWS * CC;
    u16* vb      = kb + (size_t)NROWS * CC;
    u16* statesb = vb + (size_t)NROWS * CC;             // 16*32*16384 bf16
    u16* xb      = statesb + (size_t)BB * HH * NCH * DD * DD;
    u16* retb    = xb;                                  // alias: xb dead after gemm_qkv
    u16* wcat    = xb + (size_t)NROWS * CC;             // 3 x 512x512 bf16
    u16* o_ws    = wcat + 3 * (size_t)VV * CC;

    // 1. casts / transposes / weight prep
    cvt_bf16<<<NROWS * CC / 4 / 256, 256, 0, stream>>>(x, xb);
    transpose_cvt2<<<dim3(CC / 32, VV / 32, 2), 256, 0, stream>>>(
        qw, kw, wcat, wcat + (size_t)VV * CC);
    prep_weights<<<2 * VV * CC / 256, 256, 0, stream>>>(
        basis, v_coeffs, o_coeffs, out_scale, wcat + 2 * (size_t)VV * CC, o_ws);
    // 2. merged q/k/v projection (bf16 out, double-buffered)
    gemm_qkv<<<dim3(12, NROWS / 128), 256, 0, stream>>>(xb, wcat, qb, kb, vb);
    // 3. l2norm q,k (bf16 in place)
    l2norm_bf16<<<dim3(NROWS / 4, 2), 256, 0, stream>>>(qb, kb);
    // 4. chunked linear attention (all-MFMA)
    state_local  <<<dim3(NCH, BB * HH), 256, 0, stream>>>(kb, vb, dlog, statesb);
    state_combine<<<BB * HH * 8, 256, 0, stream>>>(dlog, statesb);
    attention_fused<<<dim3(NCH, BB * HH), 256, 0, stream>>>(qb, kb, vb,
                                                            statesb, dlog, retb);
    // 5. output projection (o_ws includes out_scale), fp32 out
    gemm_out<<<dim3(CC / 128, NROWS / 128), 256, 0, stream>>>(retb, o_ws, out);
}